// Round 8
// baseline (1674.924 us; speedup 1.0000x reference)
//
#include <hip/hip_runtime.h>
#include <hip/hip_bf16.h>

#define BATCH   16384
#define NIN     784
#define NH      384
#define NLAYERS 6
#define NOUT    10
#define EPS_BN  1e-5f
#define LOSCALE 2048.0f
#define LOINV   (1.0f/2048.0f)
#define NPART_X 128
#define PSTRIDE 1024

typedef __attribute__((ext_vector_type(8))) _Float16 f16x8;
typedef __attribute__((ext_vector_type(4))) _Float16 f16x4;
typedef __attribute__((ext_vector_type(4))) float f32x4;

// ---------------------------------------------------------------------------
// Column stats over x only (input BN).  src [B, C] f32 row-major.
__global__ __launch_bounds__(256) void stats_partial(
        const float* __restrict__ src, int C,
        float* __restrict__ psum, float* __restrict__ psq) {
    int c = blockIdx.x * 256 + threadIdx.x;
    if (c >= C) return;
    int r0 = blockIdx.y * (BATCH / NPART_X);
    float s = 0.f, q = 0.f;
    for (int r = r0; r < r0 + BATCH / NPART_X; ++r) {
        float v = src[(size_t)r * C + c];
        s += v; q += v * v;
    }
    psum[blockIdx.y * PSTRIDE + c] = s;
    psq [blockIdx.y * PSTRIDE + c] = q;
}

// Reduce npart partials -> per-feature affine fold: y = a*relu(x) + c
__global__ __launch_bounds__(256) void stats_finalize(
        const float* __restrict__ psum, const float* __restrict__ psq, int C,
        int npart, const float* __restrict__ gamma, const float* __restrict__ beta,
        float* __restrict__ a_out, float* __restrict__ c_out) {
    int c = blockIdx.x * 256 + threadIdx.x;
    if (c >= C) return;
    float s = 0.f, q = 0.f;
    for (int i = 0; i < npart; ++i) { s += psum[i * PSTRIDE + c]; q += psq[i * PSTRIDE + c]; }
    const float invB = 1.f / (float)BATCH;
    float mu  = s * invB;
    float var = q * invB - mu * mu;
    float rs  = rsqrtf(var + EPS_BN);
    float g   = gamma[c];
    a_out[c] = g * rs;
    c_out[c] = beta[c] - g * mu * rs;
}

// ---------------------------------------------------------------------------
// Wp[j][n] = a[n]*W_in[j][n] split into f16 hi/lo(scaled).  4 elems/thread.
__global__ __launch_bounds__(256) void scale_win_hl(
        const float* __restrict__ W_in, const float* __restrict__ a,
        _Float16* __restrict__ whi, _Float16* __restrict__ wlo) {
    int i = blockIdx.x * 256 + threadIdx.x;
    if (i >= NH * NIN / 4) return;
    int n = (i * 4) % NIN;
    float4 wv = ((const float4*)W_in)[i];
    float v[4] = { wv.x * a[n], wv.y * a[n + 1], wv.z * a[n + 2], wv.w * a[n + 3] };
    f16x4 h4, l4;
    #pragma unroll
    for (int j = 0; j < 4; ++j) {
        _Float16 h = (_Float16)v[j];
        h4[j] = h;
        l4[j] = (_Float16)((v[j] - (float)h) * LOSCALE);
    }
    *(f16x4*)(whi + (size_t)i * 4) = h4;
    *(f16x4*)(wlo + (size_t)i * 4) = l4;
}

// f32 -> f16 hi/lo(scaled) split, 4 elems/thread (all Wd layers at once)
__global__ __launch_bounds__(256) void conv_hl(
        const float* __restrict__ src, _Float16* __restrict__ hi,
        _Float16* __restrict__ lo, int n4) {
    int i = blockIdx.x * 256 + threadIdx.x;
    if (i >= n4) return;
    float4 wv = ((const float4*)src)[i];
    float v[4] = { wv.x, wv.y, wv.z, wv.w };
    f16x4 h4, l4;
    #pragma unroll
    for (int j = 0; j < 4; ++j) {
        _Float16 h = (_Float16)v[j];
        h4[j] = h;
        l4[j] = (_Float16)((v[j] - (float)h) * LOSCALE);
    }
    *(f16x4*)(hi + (size_t)i * 4) = h4;
    *(f16x4*)(lo + (size_t)i * 4) = l4;
}

// Zero-padded gate weights: WgPad[l][st][k] (48 rows, 384 cols)
__global__ __launch_bounds__(256) void prep_wg(
        const float* __restrict__ Wg, _Float16* __restrict__ hi,
        _Float16* __restrict__ lo) {
    int idx = blockIdx.x * 256 + threadIdx.x;
    if (idx >= 5 * 48 * 384) return;
    int l = idx / (48 * 384);
    int r = idx % (48 * 384);
    int st = r / 384, k = r % 384;
    float v = 0.f;
    if (st < 36 && (k >> 6) == st / 6)
        v = Wg[l * 36 * 64 + st * 64 + (k & 63)];
    _Float16 h = (_Float16)v;
    hi[idx] = h;
    lo[idx] = (_Float16)((v - (float)h) * LOSCALE);
}

// Padded output weights: OutPad[o][k] (16 rows x 384)
__global__ __launch_bounds__(256) void prep_wout(
        const float* __restrict__ W_out, _Float16* __restrict__ hi,
        _Float16* __restrict__ lo) {
    int idx = blockIdx.x * 256 + threadIdx.x;
    if (idx >= 16 * 384) return;
    int o = idx / 384, k = idx % 384;
    float v = 0.f;
    if (o < NOUT) v = W_out[((k >> 6) * NOUT + o) * 64 + (k & 63)];
    _Float16 h = (_Float16)v;
    hi[idx] = h;
    lo[idx] = (_Float16)((v - (float)h) * LOSCALE);
}

// b'[j] = b_in[j] + sum_n c[n]*W_in[j,n]  (f32, exact)
__global__ __launch_bounds__(64) void bias_in(
        const float* __restrict__ W_in, const float* __restrict__ b_in,
        const float* __restrict__ cvec, float* __restrict__ bp) {
    int j = blockIdx.x;
    int lane = threadIdx.x;
    float s = 0.f;
    for (int n = lane; n < NIN; n += 64) s += cvec[n] * W_in[j * NIN + n];
    #pragma unroll
    for (int m = 1; m < 64; m <<= 1) s += __shfl_xor(s, m, 64);
    if (lane == 0) bp[j] = b_in[j] + s;
}

// ---------------------------------------------------------------------------
// Input GEMM (fp16x3 MFMA) with relu + fused BN-stats epilogue.
// pre[b,j] = relu(X[b,:].Wp[j,:] + bp[j]); psum/psq partial rows = bx*4+w.
// grid (B/128, 4), block 256 (4 waves). Wave: 32 batch rows (bt=2) x 96 cols.
__global__ __launch_bounds__(256, 2) void gemm_in_mfma(
        const float* __restrict__ X, const _Float16* __restrict__ Wphi,
        const _Float16* __restrict__ Wplo, const float* __restrict__ bp,
        float* __restrict__ pre, float* __restrict__ psum, float* __restrict__ psq) {
    int tid = threadIdx.x;
    int w = tid >> 6, l = tid & 63, lr = l & 15, lq = l >> 4;
    int b0 = blockIdx.x * 128 + w * 32;
    int n0 = blockIdx.y * 96;
    const float* xrow0 = X + (size_t)(b0 + lr) * NIN;
    const float* xrow1 = X + (size_t)(b0 + 16 + lr) * NIN;
    f32x4 acc[6][2], acr[6][2];
    #pragma unroll
    for (int ct = 0; ct < 6; ++ct)
        #pragma unroll
        for (int bt = 0; bt < 2; ++bt)
            #pragma unroll
            for (int r = 0; r < 4; ++r) { acc[ct][bt][r] = 0.f; acr[ct][bt][r] = 0.f; }
    for (int kc = 0; kc < 24; ++kc) {
        int k0 = kc * 32 + lq * 8;
        f16x8 ahi[2], alo[2];
        {
            float4 x0 = *(const float4*)(xrow0 + k0);
            float4 x1 = *(const float4*)(xrow0 + k0 + 4);
            float xv[8] = { x0.x, x0.y, x0.z, x0.w, x1.x, x1.y, x1.z, x1.w };
            #pragma unroll
            for (int j = 0; j < 8; ++j) {
                _Float16 h = (_Float16)xv[j];
                ahi[0][j] = h;
                alo[0][j] = (_Float16)((xv[j] - (float)h) * LOSCALE);
            }
            float4 y0 = *(const float4*)(xrow1 + k0);
            float4 y1 = *(const float4*)(xrow1 + k0 + 4);
            float yv[8] = { y0.x, y0.y, y0.z, y0.w, y1.x, y1.y, y1.z, y1.w };
            #pragma unroll
            for (int j = 0; j < 8; ++j) {
                _Float16 h = (_Float16)yv[j];
                ahi[1][j] = h;
                alo[1][j] = (_Float16)((yv[j] - (float)h) * LOSCALE);
            }
        }
        #pragma unroll
        for (int ct = 0; ct < 6; ++ct) {
            size_t off = (size_t)(n0 + ct * 16 + lr) * NIN + k0;
            f16x8 bhi = *(const f16x8*)(Wphi + off);
            f16x8 blo = *(const f16x8*)(Wplo + off);
            #pragma unroll
            for (int bt = 0; bt < 2; ++bt) {
                acc[ct][bt] = __builtin_amdgcn_mfma_f32_16x16x32_f16(ahi[bt], bhi, acc[ct][bt], 0, 0, 0);
                acr[ct][bt] = __builtin_amdgcn_mfma_f32_16x16x32_f16(ahi[bt], blo, acr[ct][bt], 0, 0, 0);
                acr[ct][bt] = __builtin_amdgcn_mfma_f32_16x16x32_f16(alo[bt], bhi, acr[ct][bt], 0, 0, 0);
            }
        }
    }
    {   // K tail 768..783 (16 valid): lanes lq>=2 contribute zeros
        f16x8 ahi[2], alo[2];
        #pragma unroll
        for (int bt = 0; bt < 2; ++bt)
            #pragma unroll
            for (int j = 0; j < 8; ++j) { ahi[bt][j] = (_Float16)0.f; alo[bt][j] = (_Float16)0.f; }
        if (lq < 2) {
            const float* xr[2] = { xrow0, xrow1 };
            #pragma unroll
            for (int bt = 0; bt < 2; ++bt) {
                float4 x0 = *(const float4*)(xr[bt] + 768 + lq * 8);
                float4 x1 = *(const float4*)(xr[bt] + 768 + lq * 8 + 4);
                float xv[8] = { x0.x, x0.y, x0.z, x0.w, x1.x, x1.y, x1.z, x1.w };
                #pragma unroll
                for (int j = 0; j < 8; ++j) {
                    _Float16 h = (_Float16)xv[j];
                    ahi[bt][j] = h;
                    alo[bt][j] = (_Float16)((xv[j] - (float)h) * LOSCALE);
                }
            }
        }
        #pragma unroll
        for (int ct = 0; ct < 6; ++ct) {
            f16x8 bhi, blo;
            #pragma unroll
            for (int j = 0; j < 8; ++j) { bhi[j] = (_Float16)0.f; blo[j] = (_Float16)0.f; }
            if (lq < 2) {
                size_t off = (size_t)(n0 + ct * 16 + lr) * NIN + 768 + lq * 8;
                bhi = *(const f16x8*)(Wphi + off);
                blo = *(const f16x8*)(Wplo + off);
            }
            #pragma unroll
            for (int bt = 0; bt < 2; ++bt) {
                acc[ct][bt] = __builtin_amdgcn_mfma_f32_16x16x32_f16(ahi[bt], bhi, acc[ct][bt], 0, 0, 0);
                acr[ct][bt] = __builtin_amdgcn_mfma_f32_16x16x32_f16(ahi[bt], blo, acr[ct][bt], 0, 0, 0);
                acr[ct][bt] = __builtin_amdgcn_mfma_f32_16x16x32_f16(alo[bt], bhi, acr[ct][bt], 0, 0, 0);
            }
        }
    }
    // epilogue: relu store + per-column stats partials (reduce rows in-lane,
    // then across lq groups via shfl_xor 16/32 — lanes {lr,lr+16,lr+32,lr+48}
    // share column n0+ct*16+lr)
    float ssum[6], ssq[6];
    #pragma unroll
    for (int ct = 0; ct < 6; ++ct) {
        int n = n0 + ct * 16 + lr;
        float bias = bp[n];
        float s = 0.f, q = 0.f;
        #pragma unroll
        for (int bt = 0; bt < 2; ++bt) {
            int brow = b0 + bt * 16 + lq * 4;
            #pragma unroll
            for (int r = 0; r < 4; ++r) {
                float v = fmaxf(acc[ct][bt][r] + LOINV * acr[ct][bt][r] + bias, 0.f);
                pre[(size_t)(brow + r) * NH + n] = v;
                s += v; q += v * v;
            }
        }
        s += __shfl_xor(s, 16, 64); s += __shfl_xor(s, 32, 64);
        q += __shfl_xor(q, 16, 64); q += __shfl_xor(q, 32, 64);
        ssum[ct] = s; ssq[ct] = q;
    }
    if (l < 16) {
        int prow = blockIdx.x * 4 + w;   // 512 partial rows
        #pragma unroll
        for (int ct = 0; ct < 6; ++ct) {
            psum[prow * PSTRIDE + n0 + ct * 16 + l] = ssum[ct];
            psq [prow * PSTRIDE + n0 + ct * 16 + l] = ssq[ct];
        }
    }
}

// ---------------------------------------------------------------------------
// Normalize + hi/lo split: y = a[j]*relu(pre)+c[j]; 8 elems/thread
// (pre already relu'd by producers; fmax is an idempotent no-op kept for safety)
__global__ __launch_bounds__(256) void norm_hl(
        const float* __restrict__ pre, const float* __restrict__ a,
        const float* __restrict__ c, _Float16* __restrict__ hi,
        _Float16* __restrict__ lo) {
    int idx = blockIdx.x * 256 + threadIdx.x;   // over B*NH/8
    int j = (idx * 8) % NH;
    float4 v0 = ((const float4*)pre)[idx * 2];
    float4 v1 = ((const float4*)pre)[idx * 2 + 1];
    float y[8] = {
        a[j+0] * fmaxf(v0.x, 0.f) + c[j+0], a[j+1] * fmaxf(v0.y, 0.f) + c[j+1],
        a[j+2] * fmaxf(v0.z, 0.f) + c[j+2], a[j+3] * fmaxf(v0.w, 0.f) + c[j+3],
        a[j+4] * fmaxf(v1.x, 0.f) + c[j+4], a[j+5] * fmaxf(v1.y, 0.f) + c[j+5],
        a[j+6] * fmaxf(v1.z, 0.f) + c[j+6], a[j+7] * fmaxf(v1.w, 0.f) + c[j+7] };
    f16x8 h8, l8;
    #pragma unroll
    for (int jj = 0; jj < 8; ++jj) {
        _Float16 h = (_Float16)y[jj];
        h8[jj] = h;
        l8[jj] = (_Float16)((y[jj] - (float)h) * LOSCALE);
    }
    *(f16x8*)(hi + (size_t)idx * 8) = h8;
    *(f16x8*)(lo + (size_t)idx * 8) = l8;
}

// ---------------------------------------------------------------------------
// Gate GEMM (fp16x3 MFMA): gateT[st][b] = clip(acts[b,:].WgPad[st,:], 0, 1);
// tg[b] (+)= sum_st gate.  grid B/64, block 256; wave: 48 st-rows x 16 b-cols.
__global__ __launch_bounds__(256, 2) void gate_mfma(
        const _Float16* __restrict__ aHi, const _Float16* __restrict__ aLo,
        const _Float16* __restrict__ WgHi, const _Float16* __restrict__ WgLo,
        float* __restrict__ gateT, float* __restrict__ tg, int firstLayer) {
    int tid = threadIdx.x;
    int w = tid >> 6, l = tid & 63, lr = l & 15, lq = l >> 4;
    int b = blockIdx.x * 64 + w * 16 + lr;
    const _Float16* arowH = aHi + (size_t)b * NH;
    const _Float16* arowL = aLo + (size_t)b * NH;
    f32x4 acc[3], acr[3];
    #pragma unroll
    for (int rt = 0; rt < 3; ++rt)
        #pragma unroll
        for (int r = 0; r < 4; ++r) { acc[rt][r] = 0.f; acr[rt][r] = 0.f; }
    #pragma unroll
    for (int kc = 0; kc < 12; ++kc) {
        int k0 = kc * 32 + lq * 8;
        f16x8 bhi = *(const f16x8*)(arowH + k0);
        f16x8 blo = *(const f16x8*)(arowL + k0);
        #pragma unroll
        for (int rt = 0; rt < 3; ++rt) {
            size_t off = (size_t)(rt * 16 + lr) * NH + k0;
            f16x8 ahi = *(const f16x8*)(WgHi + off);
            f16x8 alo = *(const f16x8*)(WgLo + off);
            acc[rt] = __builtin_amdgcn_mfma_f32_16x16x32_f16(ahi, bhi, acc[rt], 0, 0, 0);
            acr[rt] = __builtin_amdgcn_mfma_f32_16x16x32_f16(ahi, blo, acr[rt], 0, 0, 0);
            acr[rt] = __builtin_amdgcn_mfma_f32_16x16x32_f16(alo, bhi, acr[rt], 0, 0, 0);
        }
    }
    float gsum = 0.f;
    #pragma unroll
    for (int rt = 0; rt < 3; ++rt)
        #pragma unroll
        for (int r = 0; r < 4; ++r) {
            int st = rt * 16 + lq * 4 + r;
            if (st < 36) {
                float p = acc[rt][r] + LOINV * acr[rt][r];
                float g = fminf(fmaxf(p, 0.f), 1.f);
                gateT[(size_t)st * BATCH + b] = g;
                gsum += g;
            }
        }
    gsum += __shfl_xor(gsum, 16, 64);
    gsum += __shfl_xor(gsum, 32, 64);
    if (lq == 0) tg[b] = (firstLayer ? 0.f : tg[b]) + gsum;
}

// ---------------------------------------------------------------------------
// Routed layer (fp16x3 MFMA, transposed D^T[e][b]) + relu + fused stats.
// grid (B/64, 3), block 256 (4 waves). Block: 64 batch rows (ct=4), targets
// t0..t0+1 (t0 = blockIdx.y*2). Wave w: e-tile [w*16, w*16+16).
__global__ __launch_bounds__(256, 2) void layer_data_mfma(
        const _Float16* __restrict__ aHi, const _Float16* __restrict__ aLo,
        const float* __restrict__ gateT, const _Float16* __restrict__ Wdhi,
        const _Float16* __restrict__ Wdlo, const float* __restrict__ bd_l,
        float* __restrict__ pre, float* __restrict__ psum, float* __restrict__ psq) {
    int tid = threadIdx.x;
    int w = tid >> 6, l = tid & 63, lr = l & 15, lq = l >> 4;
    int b0 = blockIdx.x * 64;
    int t0 = blockIdx.y * 2;
    int e0 = w * 16;
    f32x4 acc[2][4];
    #pragma unroll
    for (int t = 0; t < 2; ++t)
        #pragma unroll
        for (int ct = 0; ct < 4; ++ct)
            #pragma unroll
            for (int r = 0; r < 4; ++r) acc[t][ct][r] = 0.f;
    for (int s = 0; s < 6; ++s) {
        f16x8 bhi[4][2], blo[4][2];   // [ct][ks]
        #pragma unroll
        for (int ct = 0; ct < 4; ++ct) {
            size_t arow = (size_t)(b0 + ct * 16 + lr) * NH + s * 64 + lq * 8;
            #pragma unroll
            for (int ks = 0; ks < 2; ++ks) {
                bhi[ct][ks] = *(const f16x8*)(aHi + arow + ks * 32);
                blo[ct][ks] = *(const f16x8*)(aLo + arow + ks * 32);
            }
        }
        #pragma unroll
        for (int tt = 0; tt < 2; ++tt) {
            int t = t0 + tt;
            float g[4];
            #pragma unroll
            for (int ct = 0; ct < 4; ++ct)
                g[ct] = gateT[(size_t)(s * 6 + t) * BATCH + b0 + ct * 16 + lr];
            size_t wb = ((size_t)(s * 6 + t) * 64 + e0 + lr) * 64 + lq * 8;
            f16x8 ah0 = *(const f16x8*)(Wdhi + wb);
            f16x8 ah1 = *(const f16x8*)(Wdhi + wb + 32);
            f16x8 al0 = *(const f16x8*)(Wdlo + wb);
            f16x8 al1 = *(const f16x8*)(Wdlo + wb + 32);
            float4 bdv = *(const float4*)(bd_l + (s * 6 + t) * 64 + e0 + lq * 4);
            #pragma unroll
            for (int ct = 0; ct < 4; ++ct) {
                f32x4 ph, pc;
                #pragma unroll
                for (int r = 0; r < 4; ++r) { ph[r] = 0.f; pc[r] = 0.f; }
                ph = __builtin_amdgcn_mfma_f32_16x16x32_f16(ah0, bhi[ct][0], ph, 0, 0, 0);
                ph = __builtin_amdgcn_mfma_f32_16x16x32_f16(ah1, bhi[ct][1], ph, 0, 0, 0);
                pc = __builtin_amdgcn_mfma_f32_16x16x32_f16(ah0, blo[ct][0], pc, 0, 0, 0);
                pc = __builtin_amdgcn_mfma_f32_16x16x32_f16(ah1, blo[ct][1], pc, 0, 0, 0);
                pc = __builtin_amdgcn_mfma_f32_16x16x32_f16(al0, bhi[ct][0], pc, 0, 0, 0);
                pc = __builtin_amdgcn_mfma_f32_16x16x32_f16(al1, bhi[ct][1], pc, 0, 0, 0);
                float bd4[4] = { bdv.x, bdv.y, bdv.z, bdv.w };
                #pragma unroll
                for (int r = 0; r < 4; ++r)
                    acc[tt][ct][r] += g[ct] * (ph[r] + LOINV * pc[r] + bd4[r]);
            }
        }
    }
    // epilogue: relu store + column stats (reduce over ct in-lane, then over
    // lr bits via shfl_xor 1/2/4/8 — column (t0+tt)*64+e0+lq*4+r is lr-invariant)
    #pragma unroll
    for (int tt = 0; tt < 2; ++tt) {
        #pragma unroll
        for (int r = 0; r < 4; ++r) {
            float s = 0.f, q = 0.f;
            #pragma unroll
            for (int ct = 0; ct < 4; ++ct) {
                float v = fmaxf(acc[tt][ct][r], 0.f);
                pre[(size_t)(b0 + ct * 16 + lr) * NH + (t0 + tt) * 64 + e0 + lq * 4 + r] = v;
                s += v; q += v * v;
            }
            s += __shfl_xor(s, 1, 64); s += __shfl_xor(s, 2, 64);
            s += __shfl_xor(s, 4, 64); s += __shfl_xor(s, 8, 64);
            q += __shfl_xor(q, 1, 64); q += __shfl_xor(q, 2, 64);
            q += __shfl_xor(q, 4, 64); q += __shfl_xor(q, 8, 64);
            if (lr == 0) {
                int col = (t0 + tt) * 64 + e0 + lq * 4 + r;
                psum[blockIdx.x * PSTRIDE + col] = s;   // 256 partial rows
                psq [blockIdx.x * PSTRIDE + col] = q;
            }
        }
    }
}

// ---------------------------------------------------------------------------
// Output head GEMM (fp16x3 MFMA) + tg copy.
__global__ __launch_bounds__(256, 2) void out_mfma(
        const _Float16* __restrict__ aHi, const _Float16* __restrict__ aLo,
        const _Float16* __restrict__ OutHi, const _Float16* __restrict__ OutLo,
        const float* __restrict__ tg, float* __restrict__ dout) {
    int tid = threadIdx.x;
    int w = tid >> 6, l = tid & 63, lr = l & 15, lq = l >> 4;
    int b = blockIdx.x * 64 + w * 16 + lr;
    const _Float16* arowH = aHi + (size_t)b * NH;
    const _Float16* arowL = aLo + (size_t)b * NH;
    f32x4 acc, acr;
    #pragma unroll
    for (int r = 0; r < 4; ++r) { acc[r] = 0.f; acr[r] = 0.f; }
    #pragma unroll
    for (int kc = 0; kc < 12; ++kc) {
        int k0 = kc * 32 + lq * 8;
        f16x8 bhi = *(const f16x8*)(arowH + k0);
        f16x8 blo = *(const f16x8*)(arowL + k0);
        size_t off = (size_t)lr * NH + k0;
        f16x8 ahi = *(const f16x8*)(OutHi + off);
        f16x8 alo = *(const f16x8*)(OutLo + off);
        acc = __builtin_amdgcn_mfma_f32_16x16x32_f16(ahi, bhi, acc, 0, 0, 0);
        acr = __builtin_amdgcn_mfma_f32_16x16x32_f16(ahi, blo, acr, 0, 0, 0);
        acr = __builtin_amdgcn_mfma_f32_16x16x32_f16(alo, bhi, acr, 0, 0, 0);
    }
    #pragma unroll
    for (int r = 0; r < 4; ++r) {
        int o = lq * 4 + r;
        if (o < NOUT)
            dout[(size_t)b * NOUT + o] = acc[r] + LOINV * acr[r];
    }
    if (lq == 0) dout[(size_t)BATCH * NOUT + b] = tg[b];
}

// ---------------------------------------------------------------------------
extern "C" void kernel_launch(void* const* d_in, const int* in_sizes, int n_in,
                              void* d_out, int out_size, void* d_ws, size_t ws_size,
                              hipStream_t stream) {
    const float* x        = (const float*)d_in[0];
    const float* gamma_in = (const float*)d_in[1];
    const float* beta_in  = (const float*)d_in[2];
    const float* W_in     = (const float*)d_in[3];
    const float* b_in     = (const float*)d_in[4];
    const float* Wg       = (const float*)d_in[5];
    const float* Wd       = (const float*)d_in[6];
    const float* bd       = (const float*)d_in[7];
    const float* gamma_h  = (const float*)d_in[8];
    const float* beta_h   = (const float*)d_in[9];
    const float* W_out    = (const float*)d_in[10];
    float* dout = (float*)d_out;
    float* ws = (float*)d_ws;

    // workspace layout (float offsets), total 15,377,408 floats = 61.5 MiB
    float* psum  = ws;                               // 512*1024
    float* psq   = ws + 524288;                      // 512*1024
    float* avec  = ws + 1048576;                     // 1024
    float* cvec  = ws + 1049600;                     // 1024
    float* bp    = ws + 1050624;                     // 1024
    float* pre   = ws + 1051648;                     // B*NH f32
    _Float16* actsHi = (_Float16*)(ws + 7343104);    // B*NH f16
    _Float16* actsLo = (_Float16*)(ws + 10488832);   // B*NH f16
    float* gateT = ws + 13634560;                    // 36*B f32
    float* tg    = ws + 14224384;                    // B
    _Float16* WpHi = (_Float16*)(ws + 14240768);     // 384*784 f16
    _Float16* WpLo = (_Float16*)(ws + 14391296);     // 384*784 f16
    _Float16* WdHiAll = (_Float16*)(ws + 14541824);  // 5*36*4096 f16
    _Float16* WdLoAll = (_Float16*)(ws + 14910464);  // 5*36*4096 f16
    _Float16* WgHiAll = (_Float16*)(ws + 15279104);  // 5*48*384 f16
    _Float16* WgLoAll = (_Float16*)(ws + 15325184);  // 5*48*384 f16
    _Float16* OutHi   = (_Float16*)(ws + 15371264);  // 16*384 f16
    _Float16* OutLo   = (_Float16*)(ws + 15374336);  // 16*384 f16

    dim3 blk(256);

    // ---- prep: input BN fold + all weight split-casts (up front)
    stats_partial<<<dim3(4, NPART_X), blk, 0, stream>>>(x, NIN, psum, psq);
    stats_finalize<<<dim3(4), blk, 0, stream>>>(psum, psq, NIN, NPART_X,
            gamma_in, beta_in, avec, cvec);
    scale_win_hl<<<dim3((NH * NIN / 4 + 255) / 256), blk, 0, stream>>>(W_in, avec, WpHi, WpLo);
    bias_in<<<dim3(NH), dim3(64), 0, stream>>>(W_in, b_in, cvec, bp);
    conv_hl<<<dim3((5 * 36 * 4096 / 4 + 255) / 256), blk, 0, stream>>>(
            Wd, WdHiAll, WdLoAll, 5 * 36 * 4096 / 4);
    prep_wg<<<dim3((5 * 48 * 384 + 255) / 256), blk, 0, stream>>>(Wg, WgHiAll, WgLoAll);
    prep_wout<<<dim3((16 * 384 + 255) / 256), blk, 0, stream>>>(W_out, OutHi, OutLo);

    // ---- input GEMM (relu + stats fused) -> pre, psum[0:512)
    gemm_in_mfma<<<dim3(BATCH / 128, 4), blk, 0, stream>>>(x, WpHi, WpLo, bp, pre, psum, psq);

    // ---- hidden layers (stats come fused from the producer GEMM)
    for (int j = 0; j < NLAYERS; ++j) {
        int npart = (j == 0) ? 512 : 256;
        stats_finalize<<<dim3(2), blk, 0, stream>>>(psum, psq, NH, npart,
                gamma_h + j * NH, beta_h + j * NH, avec, cvec);
        norm_hl<<<dim3(BATCH * NH / 8 / 256), blk, 0, stream>>>(pre, avec, cvec, actsHi, actsLo);
        if (j < NLAYERS - 1) {
            int l = j;
            gate_mfma<<<dim3(BATCH / 64), blk, 0, stream>>>(
                    actsHi, actsLo, WgHiAll + (size_t)l * 48 * 384,
                    WgLoAll + (size_t)l * 48 * 384, gateT, tg, l == 0);
            layer_data_mfma<<<dim3(BATCH / 64, 3), blk, 0, stream>>>(
                    actsHi, actsLo, gateT, WdHiAll + (size_t)l * 36 * 4096,
                    WdLoAll + (size_t)l * 36 * 4096, bd + (size_t)l * 36 * 64,
                    pre, psum, psq);
        }
    }

    // ---- output head + total_gate
    out_mfma<<<dim3(BATCH / 64), blk, 0, stream>>>(actsHi, actsLo, OutHi, OutLo, tg, dout);
}

// Round 9
// 850.508 us; speedup vs baseline: 1.9693x; 1.9693x over previous
//
#include <hip/hip_runtime.h>
#include <hip/hip_bf16.h>

#define BATCH   16384
#define NIN     784
#define NH      384
#define NLAYERS 6
#define NOUT    10
#define EPS_BN  1e-5f
#define LOSCALE 2048.0f
#define LOINV   (1.0f/2048.0f)
#define NPART   128
#define PSTRIDE 1024

typedef __attribute__((ext_vector_type(8))) _Float16 f16x8;
typedef __attribute__((ext_vector_type(4))) _Float16 f16x4;
typedef __attribute__((ext_vector_type(4))) float f32x4;

// ---------------------------------------------------------------------------
// Column stats (two-stage, deterministic).  src [B, C] f32 row-major.
__global__ __launch_bounds__(256) void stats_partial(
        const float* __restrict__ src, int C, int applyRelu,
        float* __restrict__ psum, float* __restrict__ psq) {
    int c = blockIdx.x * 256 + threadIdx.x;
    if (c >= C) return;
    int r0 = blockIdx.y * (BATCH / NPART);
    float s = 0.f, q = 0.f;
    for (int r = r0; r < r0 + BATCH / NPART; ++r) {
        float v = src[(size_t)r * C + c];
        if (applyRelu) v = fmaxf(v, 0.f);
        s += v; q += v * v;
    }
    psum[blockIdx.y * PSTRIDE + c] = s;
    psq [blockIdx.y * PSTRIDE + c] = q;
}

__global__ __launch_bounds__(256) void stats_finalize(
        const float* __restrict__ psum, const float* __restrict__ psq, int C,
        const float* __restrict__ gamma, const float* __restrict__ beta,
        float* __restrict__ a_out, float* __restrict__ c_out) {
    int c = blockIdx.x * 256 + threadIdx.x;
    if (c >= C) return;
    float s = 0.f, q = 0.f;
    for (int i = 0; i < NPART; ++i) { s += psum[i * PSTRIDE + c]; q += psq[i * PSTRIDE + c]; }
    const float invB = 1.f / (float)BATCH;
    float mu  = s * invB;
    float var = q * invB - mu * mu;
    float rs  = rsqrtf(var + EPS_BN);
    float g   = gamma[c];
    a_out[c] = g * rs;
    c_out[c] = beta[c] - g * mu * rs;
}

// ---------------------------------------------------------------------------
// Wp[j][n] = a[n]*W_in[j][n] split into f16 hi/lo(scaled).  4 elems/thread.
__global__ __launch_bounds__(256) void scale_win_hl(
        const float* __restrict__ W_in, const float* __restrict__ a,
        _Float16* __restrict__ whi, _Float16* __restrict__ wlo) {
    int i = blockIdx.x * 256 + threadIdx.x;
    if (i >= NH * NIN / 4) return;
    int n = (i * 4) % NIN;
    float4 wv = ((const float4*)W_in)[i];
    float v[4] = { wv.x * a[n], wv.y * a[n + 1], wv.z * a[n + 2], wv.w * a[n + 3] };
    f16x4 h4, l4;
    #pragma unroll
    for (int j = 0; j < 4; ++j) {
        _Float16 h = (_Float16)v[j];
        h4[j] = h;
        l4[j] = (_Float16)((v[j] - (float)h) * LOSCALE);
    }
    *(f16x4*)(whi + (size_t)i * 4) = h4;
    *(f16x4*)(wlo + (size_t)i * 4) = l4;
}

// f32 -> f16 hi/lo(scaled) split, 4 elems/thread (all Wd layers at once)
__global__ __launch_bounds__(256) void conv_hl(
        const float* __restrict__ src, _Float16* __restrict__ hi,
        _Float16* __restrict__ lo, int n4) {
    int i = blockIdx.x * 256 + threadIdx.x;
    if (i >= n4) return;
    float4 wv = ((const float4*)src)[i];
    float v[4] = { wv.x, wv.y, wv.z, wv.w };
    f16x4 h4, l4;
    #pragma unroll
    for (int j = 0; j < 4; ++j) {
        _Float16 h = (_Float16)v[j];
        h4[j] = h;
        l4[j] = (_Float16)((v[j] - (float)h) * LOSCALE);
    }
    *(f16x4*)(hi + (size_t)i * 4) = h4;
    *(f16x4*)(lo + (size_t)i * 4) = l4;
}

// Zero-padded gate weights: WgPad[l][st][k] (48 rows, 384 cols)
__global__ __launch_bounds__(256) void prep_wg(
        const float* __restrict__ Wg, _Float16* __restrict__ hi,
        _Float16* __restrict__ lo) {
    int idx = blockIdx.x * 256 + threadIdx.x;
    if (idx >= 5 * 48 * 384) return;
    int l = idx / (48 * 384);
    int r = idx % (48 * 384);
    int st = r / 384, k = r % 384;
    float v = 0.f;
    if (st < 36 && (k >> 6) == st / 6)
        v = Wg[l * 36 * 64 + st * 64 + (k & 63)];
    _Float16 h = (_Float16)v;
    hi[idx] = h;
    lo[idx] = (_Float16)((v - (float)h) * LOSCALE);
}

// Padded output weights: OutPad[o][k] (16 rows x 384)
__global__ __launch_bounds__(256) void prep_wout(
        const float* __restrict__ W_out, _Float16* __restrict__ hi,
        _Float16* __restrict__ lo) {
    int idx = blockIdx.x * 256 + threadIdx.x;
    if (idx >= 16 * 384) return;
    int o = idx / 384, k = idx % 384;
    float v = 0.f;
    if (o < NOUT) v = W_out[((k >> 6) * NOUT + o) * 64 + (k & 63)];
    _Float16 h = (_Float16)v;
    hi[idx] = h;
    lo[idx] = (_Float16)((v - (float)h) * LOSCALE);
}

// b'[j] = b_in[j] + sum_n c[n]*W_in[j,n]  (f32, exact)
__global__ __launch_bounds__(64) void bias_in(
        const float* __restrict__ W_in, const float* __restrict__ b_in,
        const float* __restrict__ cvec, float* __restrict__ bp) {
    int j = blockIdx.x;
    int lane = threadIdx.x;
    float s = 0.f;
    for (int n = lane; n < NIN; n += 64) s += cvec[n] * W_in[j * NIN + n];
    #pragma unroll
    for (int m = 1; m < 64; m <<= 1) s += __shfl_xor(s, m, 64);
    if (lane == 0) bp[j] = b_in[j] + s;
}

// ---------------------------------------------------------------------------
// Input GEMM (fp16x3 MFMA): pre[b,j] = X[b,:].Wp[j,:] + bp[j]   (round-7 exact)
// grid (B/128, 4), block 256 (4 waves). Wave: 32 batch rows (bt=2) x 96 cols.
__global__ __launch_bounds__(256, 2) void gemm_in_mfma(
        const float* __restrict__ X, const _Float16* __restrict__ Wphi,
        const _Float16* __restrict__ Wplo, const float* __restrict__ bp,
        float* __restrict__ pre) {
    int tid = threadIdx.x;
    int w = tid >> 6, l = tid & 63, lr = l & 15, lq = l >> 4;
    int b0 = blockIdx.x * 128 + w * 32;
    int n0 = blockIdx.y * 96;
    const float* xrow0 = X + (size_t)(b0 + lr) * NIN;
    const float* xrow1 = X + (size_t)(b0 + 16 + lr) * NIN;
    f32x4 acc[6][2], acr[6][2];
    #pragma unroll
    for (int ct = 0; ct < 6; ++ct)
        #pragma unroll
        for (int bt = 0; bt < 2; ++bt)
            #pragma unroll
            for (int r = 0; r < 4; ++r) { acc[ct][bt][r] = 0.f; acr[ct][bt][r] = 0.f; }
    for (int kc = 0; kc < 24; ++kc) {
        int k0 = kc * 32 + lq * 8;
        f16x8 ahi[2], alo[2];
        {
            float4 x0 = *(const float4*)(xrow0 + k0);
            float4 x1 = *(const float4*)(xrow0 + k0 + 4);
            float xv[8] = { x0.x, x0.y, x0.z, x0.w, x1.x, x1.y, x1.z, x1.w };
            #pragma unroll
            for (int j = 0; j < 8; ++j) {
                _Float16 h = (_Float16)xv[j];
                ahi[0][j] = h;
                alo[0][j] = (_Float16)((xv[j] - (float)h) * LOSCALE);
            }
            float4 y0 = *(const float4*)(xrow1 + k0);
            float4 y1 = *(const float4*)(xrow1 + k0 + 4);
            float yv[8] = { y0.x, y0.y, y0.z, y0.w, y1.x, y1.y, y1.z, y1.w };
            #pragma unroll
            for (int j = 0; j < 8; ++j) {
                _Float16 h = (_Float16)yv[j];
                ahi[1][j] = h;
                alo[1][j] = (_Float16)((yv[j] - (float)h) * LOSCALE);
            }
        }
        #pragma unroll
        for (int ct = 0; ct < 6; ++ct) {
            size_t off = (size_t)(n0 + ct * 16 + lr) * NIN + k0;
            f16x8 bhi = *(const f16x8*)(Wphi + off);
            f16x8 blo = *(const f16x8*)(Wplo + off);
            #pragma unroll
            for (int bt = 0; bt < 2; ++bt) {
                acc[ct][bt] = __builtin_amdgcn_mfma_f32_16x16x32_f16(ahi[bt], bhi, acc[ct][bt], 0, 0, 0);
                acr[ct][bt] = __builtin_amdgcn_mfma_f32_16x16x32_f16(ahi[bt], blo, acr[ct][bt], 0, 0, 0);
                acr[ct][bt] = __builtin_amdgcn_mfma_f32_16x16x32_f16(alo[bt], bhi, acr[ct][bt], 0, 0, 0);
            }
        }
    }
    {   // K tail 768..783 (16 valid): lanes lq>=2 contribute zeros
        f16x8 ahi[2], alo[2];
        #pragma unroll
        for (int bt = 0; bt < 2; ++bt)
            #pragma unroll
            for (int j = 0; j < 8; ++j) { ahi[bt][j] = (_Float16)0.f; alo[bt][j] = (_Float16)0.f; }
        if (lq < 2) {
            const float* xr[2] = { xrow0, xrow1 };
            #pragma unroll
            for (int bt = 0; bt < 2; ++bt) {
                float4 x0 = *(const float4*)(xr[bt] + 768 + lq * 8);
                float4 x1 = *(const float4*)(xr[bt] + 768 + lq * 8 + 4);
                float xv[8] = { x0.x, x0.y, x0.z, x0.w, x1.x, x1.y, x1.z, x1.w };
                #pragma unroll
                for (int j = 0; j < 8; ++j) {
                    _Float16 h = (_Float16)xv[j];
                    ahi[bt][j] = h;
                    alo[bt][j] = (_Float16)((xv[j] - (float)h) * LOSCALE);
                }
            }
        }
        #pragma unroll
        for (int ct = 0; ct < 6; ++ct) {
            f16x8 bhi, blo;
            #pragma unroll
            for (int j = 0; j < 8; ++j) { bhi[j] = (_Float16)0.f; blo[j] = (_Float16)0.f; }
            if (lq < 2) {
                size_t off = (size_t)(n0 + ct * 16 + lr) * NIN + 768 + lq * 8;
                bhi = *(const f16x8*)(Wphi + off);
                blo = *(const f16x8*)(Wplo + off);
            }
            #pragma unroll
            for (int bt = 0; bt < 2; ++bt) {
                acc[ct][bt] = __builtin_amdgcn_mfma_f32_16x16x32_f16(ahi[bt], bhi, acc[ct][bt], 0, 0, 0);
                acr[ct][bt] = __builtin_amdgcn_mfma_f32_16x16x32_f16(ahi[bt], blo, acr[ct][bt], 0, 0, 0);
                acr[ct][bt] = __builtin_amdgcn_mfma_f32_16x16x32_f16(alo[bt], bhi, acr[ct][bt], 0, 0, 0);
            }
        }
    }
    #pragma unroll
    for (int ct = 0; ct < 6; ++ct) {
        int n = n0 + ct * 16 + lr;
        float bias = bp[n];
        #pragma unroll
        for (int bt = 0; bt < 2; ++bt) {
            int brow = b0 + bt * 16 + lq * 4;
            #pragma unroll
            for (int r = 0; r < 4; ++r)
                pre[(size_t)(brow + r) * NH + n] = acc[ct][bt][r] + LOINV * acr[ct][bt][r] + bias;
        }
    }
}

// ---------------------------------------------------------------------------
// Normalize + hi/lo split (used for the last layer only): y = a*relu(pre)+c
__global__ __launch_bounds__(256) void norm_hl(
        const float* __restrict__ pre, const float* __restrict__ a,
        const float* __restrict__ c, _Float16* __restrict__ hi,
        _Float16* __restrict__ lo) {
    int idx = blockIdx.x * 256 + threadIdx.x;   // over B*NH/8
    int j = (idx * 8) % NH;
    float4 v0 = ((const float4*)pre)[idx * 2];
    float4 v1 = ((const float4*)pre)[idx * 2 + 1];
    float y[8] = {
        a[j+0] * fmaxf(v0.x, 0.f) + c[j+0], a[j+1] * fmaxf(v0.y, 0.f) + c[j+1],
        a[j+2] * fmaxf(v0.z, 0.f) + c[j+2], a[j+3] * fmaxf(v0.w, 0.f) + c[j+3],
        a[j+4] * fmaxf(v1.x, 0.f) + c[j+4], a[j+5] * fmaxf(v1.y, 0.f) + c[j+5],
        a[j+6] * fmaxf(v1.z, 0.f) + c[j+6], a[j+7] * fmaxf(v1.w, 0.f) + c[j+7] };
    f16x8 h8, l8;
    #pragma unroll
    for (int jj = 0; jj < 8; ++jj) {
        _Float16 h = (_Float16)y[jj];
        h8[jj] = h;
        l8[jj] = (_Float16)((y[jj] - (float)h) * LOSCALE);
    }
    *(f16x8*)(hi + (size_t)idx * 8) = h8;
    *(f16x8*)(lo + (size_t)idx * 8) = l8;
}

// ---------------------------------------------------------------------------
// Fused norm + gate GEMM: per thread, normalize 8-feature chunks of one batch
// row (writing actsHi/Lo) and feed them directly as the gate MFMA B-operand.
// gateT[st][b] = clip(acts[b,:].WgPad[st,:],0,1); tg accumulate.
// grid B/64, block 256 (4 waves); wave: 48 st-rows x 16 b-cols.
__global__ __launch_bounds__(256, 2) void normgate_mfma(
        const float* __restrict__ pre, const float* __restrict__ a,
        const float* __restrict__ c, const _Float16* __restrict__ WgHi,
        const _Float16* __restrict__ WgLo, _Float16* __restrict__ aHi,
        _Float16* __restrict__ aLo, float* __restrict__ gateT,
        float* __restrict__ tg, int firstLayer) {
    int tid = threadIdx.x;
    int w = tid >> 6, l = tid & 63, lr = l & 15, lq = l >> 4;
    int b = blockIdx.x * 64 + w * 16 + lr;
    const float* prow = pre + (size_t)b * NH;
    f32x4 acc[3], acr[3];
    #pragma unroll
    for (int rt = 0; rt < 3; ++rt)
        #pragma unroll
        for (int r = 0; r < 4; ++r) { acc[rt][r] = 0.f; acr[rt][r] = 0.f; }
    #pragma unroll
    for (int kc = 0; kc < 12; ++kc) {
        int k0 = kc * 32 + lq * 8;
        float4 v0 = *(const float4*)(prow + k0);
        float4 v1 = *(const float4*)(prow + k0 + 4);
        float4 a0 = *(const float4*)(a + k0);
        float4 a1 = *(const float4*)(a + k0 + 4);
        float4 c0 = *(const float4*)(c + k0);
        float4 c1 = *(const float4*)(c + k0 + 4);
        float y[8] = {
            a0.x * fmaxf(v0.x, 0.f) + c0.x, a0.y * fmaxf(v0.y, 0.f) + c0.y,
            a0.z * fmaxf(v0.z, 0.f) + c0.z, a0.w * fmaxf(v0.w, 0.f) + c0.w,
            a1.x * fmaxf(v1.x, 0.f) + c1.x, a1.y * fmaxf(v1.y, 0.f) + c1.y,
            a1.z * fmaxf(v1.z, 0.f) + c1.z, a1.w * fmaxf(v1.w, 0.f) + c1.w };
        f16x8 bhi, blo;
        #pragma unroll
        for (int j = 0; j < 8; ++j) {
            _Float16 h = (_Float16)y[j];
            bhi[j] = h;
            blo[j] = (_Float16)((y[j] - (float)h) * LOSCALE);
        }
        *(f16x8*)(aHi + (size_t)b * NH + k0) = bhi;
        *(f16x8*)(aLo + (size_t)b * NH + k0) = blo;
        #pragma unroll
        for (int rt = 0; rt < 3; ++rt) {
            size_t off = (size_t)(rt * 16 + lr) * NH + k0;
            f16x8 whi = *(const f16x8*)(WgHi + off);
            f16x8 wlo = *(const f16x8*)(WgLo + off);
            acc[rt] = __builtin_amdgcn_mfma_f32_16x16x32_f16(whi, bhi, acc[rt], 0, 0, 0);
            acr[rt] = __builtin_amdgcn_mfma_f32_16x16x32_f16(whi, blo, acr[rt], 0, 0, 0);
            acr[rt] = __builtin_amdgcn_mfma_f32_16x16x32_f16(wlo, bhi, acr[rt], 0, 0, 0);
        }
    }
    float gsum = 0.f;
    #pragma unroll
    for (int rt = 0; rt < 3; ++rt)
        #pragma unroll
        for (int r = 0; r < 4; ++r) {
            int st = rt * 16 + lq * 4 + r;
            if (st < 36) {
                float p = acc[rt][r] + LOINV * acr[rt][r];
                float g = fminf(fmaxf(p, 0.f), 1.f);
                gateT[(size_t)st * BATCH + b] = g;
                gsum += g;
            }
        }
    gsum += __shfl_xor(gsum, 16, 64);
    gsum += __shfl_xor(gsum, 32, 64);
    if (lq == 0) tg[b] = (firstLayer ? 0.f : tg[b]) + gsum;
}

// ---------------------------------------------------------------------------
// Routed layer (fp16x3 MFMA, transposed D^T[e][b]).  Round-7 body, t-split 3.
// grid (B/64, 3), block 256 (4 waves). Block: 64 batch rows (ct=4), targets
// t0..t0+1 (t0 = blockIdx.y*2). Wave w: e-tile [w*16, w*16+16).
__global__ __launch_bounds__(256, 2) void layer_data_mfma(
        const _Float16* __restrict__ aHi, const _Float16* __restrict__ aLo,
        const float* __restrict__ gateT, const _Float16* __restrict__ Wdhi,
        const _Float16* __restrict__ Wdlo, const float* __restrict__ bd_l,
        float* __restrict__ pre) {
    int tid = threadIdx.x;
    int w = tid >> 6, l = tid & 63, lr = l & 15, lq = l >> 4;
    int b0 = blockIdx.x * 64;
    int t0 = blockIdx.y * 2;
    int e0 = w * 16;
    f32x4 acc[2][4];
    #pragma unroll
    for (int t = 0; t < 2; ++t)
        #pragma unroll
        for (int ct = 0; ct < 4; ++ct)
            #pragma unroll
            for (int r = 0; r < 4; ++r) acc[t][ct][r] = 0.f;
    for (int s = 0; s < 6; ++s) {
        f16x8 bhi[4][2], blo[4][2];   // [ct][ks]
        #pragma unroll
        for (int ct = 0; ct < 4; ++ct) {
            size_t arow = (size_t)(b0 + ct * 16 + lr) * NH + s * 64 + lq * 8;
            #pragma unroll
            for (int ks = 0; ks < 2; ++ks) {
                bhi[ct][ks] = *(const f16x8*)(aHi + arow + ks * 32);
                blo[ct][ks] = *(const f16x8*)(aLo + arow + ks * 32);
            }
        }
        #pragma unroll
        for (int tt = 0; tt < 2; ++tt) {
            int t = t0 + tt;
            float g[4];
            #pragma unroll
            for (int ct = 0; ct < 4; ++ct)
                g[ct] = gateT[(size_t)(s * 6 + t) * BATCH + b0 + ct * 16 + lr];
            size_t wb = ((size_t)(s * 6 + t) * 64 + e0 + lr) * 64 + lq * 8;
            f16x8 ah0 = *(const f16x8*)(Wdhi + wb);
            f16x8 ah1 = *(const f16x8*)(Wdhi + wb + 32);
            f16x8 al0 = *(const f16x8*)(Wdlo + wb);
            f16x8 al1 = *(const f16x8*)(Wdlo + wb + 32);
            float bdv[4];
            #pragma unroll
            for (int r = 0; r < 4; ++r)
                bdv[r] = bd_l[(s * 6 + t) * 64 + e0 + lq * 4 + r];
            #pragma unroll
            for (int ct = 0; ct < 4; ++ct) {
                f32x4 ph, pc;
                #pragma unroll
                for (int r = 0; r < 4; ++r) { ph[r] = 0.f; pc[r] = 0.f; }
                ph = __builtin_amdgcn_mfma_f32_16x16x32_f16(ah0, bhi[ct][0], ph, 0, 0, 0);
                ph = __builtin_amdgcn_mfma_f32_16x16x32_f16(ah1, bhi[ct][1], ph, 0, 0, 0);
                pc = __builtin_amdgcn_mfma_f32_16x16x32_f16(ah0, blo[ct][0], pc, 0, 0, 0);
                pc = __builtin_amdgcn_mfma_f32_16x16x32_f16(ah1, blo[ct][1], pc, 0, 0, 0);
                pc = __builtin_amdgcn_mfma_f32_16x16x32_f16(al0, bhi[ct][0], pc, 0, 0, 0);
                pc = __builtin_amdgcn_mfma_f32_16x16x32_f16(al1, bhi[ct][1], pc, 0, 0, 0);
                #pragma unroll
                for (int r = 0; r < 4; ++r)
                    acc[tt][ct][r] += g[ct] * (ph[r] + LOINV * pc[r] + bdv[r]);
            }
        }
    }
    #pragma unroll
    for (int tt = 0; tt < 2; ++tt)
        #pragma unroll
        for (int ct = 0; ct < 4; ++ct)
            #pragma unroll
            for (int r = 0; r < 4; ++r)
                pre[(size_t)(b0 + ct * 16 + lr) * NH + (t0 + tt) * 64 + e0 + lq * 4 + r]
                    = acc[tt][ct][r];
}

// ---------------------------------------------------------------------------
// Output head GEMM (fp16x3 MFMA) + tg copy.
__global__ __launch_bounds__(256, 2) void out_mfma(
        const _Float16* __restrict__ aHi, const _Float16* __restrict__ aLo,
        const _Float16* __restrict__ OutHi, const _Float16* __restrict__ OutLo,
        const float* __restrict__ tg, float* __restrict__ dout) {
    int tid = threadIdx.x;
    int w = tid >> 6, l = tid & 63, lr = l & 15, lq = l >> 4;
    int b = blockIdx.x * 64 + w * 16 + lr;
    const _Float16* arowH = aHi + (size_t)b * NH;
    const _Float16* arowL = aLo + (size_t)b * NH;
    f32x4 acc, acr;
    #pragma unroll
    for (int r = 0; r < 4; ++r) { acc[r] = 0.f; acr[r] = 0.f; }
    #pragma unroll
    for (int kc = 0; kc < 12; ++kc) {
        int k0 = kc * 32 + lq * 8;
        f16x8 bhi = *(const f16x8*)(arowH + k0);
        f16x8 blo = *(const f16x8*)(arowL + k0);
        size_t off = (size_t)lr * NH + k0;
        f16x8 ahi = *(const f16x8*)(OutHi + off);
        f16x8 alo = *(const f16x8*)(OutLo + off);
        acc = __builtin_amdgcn_mfma_f32_16x16x32_f16(ahi, bhi, acc, 0, 0, 0);
        acr = __builtin_amdgcn_mfma_f32_16x16x32_f16(ahi, blo, acr, 0, 0, 0);
        acr = __builtin_amdgcn_mfma_f32_16x16x32_f16(alo, bhi, acr, 0, 0, 0);
    }
    #pragma unroll
    for (int r = 0; r < 4; ++r) {
        int o = lq * 4 + r;
        if (o < NOUT)
            dout[(size_t)b * NOUT + o] = acc[r] + LOINV * acr[r];
    }
    if (lq == 0) dout[(size_t)BATCH * NOUT + b] = tg[b];
}

// ---------------------------------------------------------------------------
extern "C" void kernel_launch(void* const* d_in, const int* in_sizes, int n_in,
                              void* d_out, int out_size, void* d_ws, size_t ws_size,
                              hipStream_t stream) {
    const float* x        = (const float*)d_in[0];
    const float* gamma_in = (const float*)d_in[1];
    const float* beta_in  = (const float*)d_in[2];
    const float* W_in     = (const float*)d_in[3];
    const float* b_in     = (const float*)d_in[4];
    const float* Wg       = (const float*)d_in[5];
    const float* Wd       = (const float*)d_in[6];
    const float* bd       = (const float*)d_in[7];
    const float* gamma_h  = (const float*)d_in[8];
    const float* beta_h   = (const float*)d_in[9];
    const float* W_out    = (const float*)d_in[10];
    float* dout = (float*)d_out;
    float* ws = (float*)d_ws;

    // workspace layout (float offsets), total ~14.59M floats = 58.4 MiB
    float* psum  = ws;                              // 128*1024
    float* psq   = ws + 131072;                     // 128*1024
    float* avec  = ws + 262144;                     // 1024
    float* cvec  = ws + 263168;                     // 1024
    float* bp    = ws + 264192;                     // 1024
    float* pre   = ws + 265216;                     // B*NH f32
    _Float16* actsHi = (_Float16*)(ws + 6556672);   // B*NH f16
    _Float16* actsLo = (_Float16*)(ws + 9702400);   // B*NH f16
    float* gateT = ws + 12848128;                   // 36*B f32
    float* tg    = ws + 13437952;                   // B
    _Float16* WpHi = (_Float16*)(ws + 13454336);    // 384*784 f16
    _Float16* WpLo = (_Float16*)(ws + 13604864);    // 384*784 f16
    _Float16* WdHiAll = (_Float16*)(ws + 13755392); // 5*36*4096 f16
    _Float16* WdLoAll = (_Float16*)(ws + 14124032); // 5*36*4096 f16
    _Float16* WgHiAll = (_Float16*)(ws + 14492672); // 5*48*384 f16
    _Float16* WgLoAll = (_Float16*)(ws + 14538752); // 5*48*384 f16
    _Float16* OutHi   = (_Float16*)(ws + 14584832); // 16*384 f16
    _Float16* OutLo   = (_Float16*)(ws + 14587904); // 16*384 f16

    dim3 blk(256);

    // ---- prep: input BN fold + all weight split-casts (up front)
    stats_partial<<<dim3(4, NPART), blk, 0, stream>>>(x, NIN, 0, psum, psq);
    stats_finalize<<<dim3(4), blk, 0, stream>>>(psum, psq, NIN, gamma_in, beta_in, avec, cvec);
    scale_win_hl<<<dim3((NH * NIN / 4 + 255) / 256), blk, 0, stream>>>(W_in, avec, WpHi, WpLo);
    bias_in<<<dim3(NH), dim3(64), 0, stream>>>(W_in, b_in, cvec, bp);
    conv_hl<<<dim3((5 * 36 * 4096 / 4 + 255) / 256), blk, 0, stream>>>(
            Wd, WdHiAll, WdLoAll, 5 * 36 * 4096 / 4);
    prep_wg<<<dim3((5 * 48 * 384 + 255) / 256), blk, 0, stream>>>(Wg, WgHiAll, WgLoAll);
    prep_wout<<<dim3((16 * 384 + 255) / 256), blk, 0, stream>>>(W_out, OutHi, OutLo);

    // ---- input GEMM (fp16x3 MFMA) -> pre f32
    gemm_in_mfma<<<dim3(BATCH / 128, 4), blk, 0, stream>>>(x, WpHi, WpLo, bp, pre);

    // ---- hidden layers
    for (int j = 0; j < NLAYERS; ++j) {
        stats_partial<<<dim3(2, NPART), blk, 0, stream>>>(pre, NH, 1, psum, psq);
        stats_finalize<<<dim3(2), blk, 0, stream>>>(psum, psq, NH,
                gamma_h + j * NH, beta_h + j * NH, avec, cvec);
        if (j < NLAYERS - 1) {
            int l = j;
            normgate_mfma<<<dim3(BATCH / 64), blk, 0, stream>>>(
                    pre, avec, cvec, WgHiAll + (size_t)l * 48 * 384,
                    WgLoAll + (size_t)l * 48 * 384, actsHi, actsLo, gateT, tg, l == 0);
            layer_data_mfma<<<dim3(BATCH / 64, 3), blk, 0, stream>>>(
                    actsHi, actsLo, gateT, WdHiAll + (size_t)l * 36 * 4096,
                    WdLoAll + (size_t)l * 36 * 4096, bd + (size_t)l * 36 * 64, pre);
        } else {
            norm_hl<<<dim3(BATCH * NH / 8 / 256), blk, 0, stream>>>(
                    pre, avec, cvec, actsHi, actsLo);
        }
    }

    // ---- output head + total_gate
    out_mfma<<<dim3(BATCH / 64), blk, 0, stream>>>(actsHi, actsLo, OutHi, OutLo, tg, dout);
}

// Round 10
// 607.658 us; speedup vs baseline: 2.7564x; 1.3996x over previous
//
#include <hip/hip_runtime.h>
#include <hip/hip_bf16.h>

#define BATCH   16384
#define NIN     784
#define NH      384
#define NLAYERS 6
#define NOUT    10
#define EPS_BN  1e-5f
#define LOSCALE 2048.0f
#define LOINV   (1.0f/2048.0f)
#define NPART   128
#define PSTRIDE 1024

typedef __attribute__((ext_vector_type(8))) _Float16 f16x8;
typedef __attribute__((ext_vector_type(4))) _Float16 f16x4;
typedef __attribute__((ext_vector_type(4))) float f32x4;

// ---------------------------------------------------------------------------
// Column stats (two-stage, deterministic).  src [B, C] f32 row-major.
__global__ __launch_bounds__(256) void stats_partial(
        const float* __restrict__ src, int C, int applyRelu,
        float* __restrict__ psum, float* __restrict__ psq) {
    int c = blockIdx.x * 256 + threadIdx.x;
    if (c >= C) return;
    int r0 = blockIdx.y * (BATCH / NPART);
    float s = 0.f, q = 0.f;
    for (int r = r0; r < r0 + BATCH / NPART; ++r) {
        float v = src[(size_t)r * C + c];
        if (applyRelu) v = fmaxf(v, 0.f);
        s += v; q += v * v;
    }
    psum[blockIdx.y * PSTRIDE + c] = s;
    psq [blockIdx.y * PSTRIDE + c] = q;
}

__global__ __launch_bounds__(256) void stats_finalize(
        const float* __restrict__ psum, const float* __restrict__ psq, int C,
        const float* __restrict__ gamma, const float* __restrict__ beta,
        float* __restrict__ a_out, float* __restrict__ c_out) {
    int c = blockIdx.x * 256 + threadIdx.x;
    if (c >= C) return;
    float s = 0.f, q = 0.f;
    for (int i = 0; i < NPART; ++i) { s += psum[i * PSTRIDE + c]; q += psq[i * PSTRIDE + c]; }
    const float invB = 1.f / (float)BATCH;
    float mu  = s * invB;
    float var = q * invB - mu * mu;
    float rs  = rsqrtf(var + EPS_BN);
    float g   = gamma[c];
    a_out[c] = g * rs;
    c_out[c] = beta[c] - g * mu * rs;
}

// ---------------------------------------------------------------------------
// Wp[j][n] = a[n]*W_in[j][n] split into f16 hi/lo(scaled).  4 elems/thread.
__global__ __launch_bounds__(256) void scale_win_hl(
        const float* __restrict__ W_in, const float* __restrict__ a,
        _Float16* __restrict__ whi, _Float16* __restrict__ wlo) {
    int i = blockIdx.x * 256 + threadIdx.x;
    if (i >= NH * NIN / 4) return;
    int n = (i * 4) % NIN;
    float4 wv = ((const float4*)W_in)[i];
    float v[4] = { wv.x * a[n], wv.y * a[n + 1], wv.z * a[n + 2], wv.w * a[n + 3] };
    f16x4 h4, l4;
    #pragma unroll
    for (int j = 0; j < 4; ++j) {
        _Float16 h = (_Float16)v[j];
        h4[j] = h;
        l4[j] = (_Float16)((v[j] - (float)h) * LOSCALE);
    }
    *(f16x4*)(whi + (size_t)i * 4) = h4;
    *(f16x4*)(wlo + (size_t)i * 4) = l4;
}

// f32 -> f16 hi/lo(scaled) split, 4 elems/thread (all Wd layers at once)
__global__ __launch_bounds__(256) void conv_hl(
        const float* __restrict__ src, _Float16* __restrict__ hi,
        _Float16* __restrict__ lo, int n4) {
    int i = blockIdx.x * 256 + threadIdx.x;
    if (i >= n4) return;
    float4 wv = ((const float4*)src)[i];
    float v[4] = { wv.x, wv.y, wv.z, wv.w };
    f16x4 h4, l4;
    #pragma unroll
    for (int j = 0; j < 4; ++j) {
        _Float16 h = (_Float16)v[j];
        h4[j] = h;
        l4[j] = (_Float16)((v[j] - (float)h) * LOSCALE);
    }
    *(f16x4*)(hi + (size_t)i * 4) = h4;
    *(f16x4*)(lo + (size_t)i * 4) = l4;
}

// Zero-padded gate weights: WgPad[l][st][k] (48 rows, 384 cols)
__global__ __launch_bounds__(256) void prep_wg(
        const float* __restrict__ Wg, _Float16* __restrict__ hi,
        _Float16* __restrict__ lo) {
    int idx = blockIdx.x * 256 + threadIdx.x;
    if (idx >= 5 * 48 * 384) return;
    int l = idx / (48 * 384);
    int r = idx % (48 * 384);
    int st = r / 384, k = r % 384;
    float v = 0.f;
    if (st < 36 && (k >> 6) == st / 6)
        v = Wg[l * 36 * 64 + st * 64 + (k & 63)];
    _Float16 h = (_Float16)v;
    hi[idx] = h;
    lo[idx] = (_Float16)((v - (float)h) * LOSCALE);
}

// Padded output weights: OutPad[o][k] (16 rows x 384)
__global__ __launch_bounds__(256) void prep_wout(
        const float* __restrict__ W_out, _Float16* __restrict__ hi,
        _Float16* __restrict__ lo) {
    int idx = blockIdx.x * 256 + threadIdx.x;
    if (idx >= 16 * 384) return;
    int o = idx / 384, k = idx % 384;
    float v = 0.f;
    if (o < NOUT) v = W_out[((k >> 6) * NOUT + o) * 64 + (k & 63)];
    _Float16 h = (_Float16)v;
    hi[idx] = h;
    lo[idx] = (_Float16)((v - (float)h) * LOSCALE);
}

// b'[j] = b_in[j] + sum_n c[n]*W_in[j,n]  (f32, exact)
__global__ __launch_bounds__(64) void bias_in(
        const float* __restrict__ W_in, const float* __restrict__ b_in,
        const float* __restrict__ cvec, float* __restrict__ bp) {
    int j = blockIdx.x;
    int lane = threadIdx.x;
    float s = 0.f;
    for (int n = lane; n < NIN; n += 64) s += cvec[n] * W_in[j * NIN + n];
    #pragma unroll
    for (int m = 1; m < 64; m <<= 1) s += __shfl_xor(s, m, 64);
    if (lane == 0) bp[j] = b_in[j] + s;
}

// ---------------------------------------------------------------------------
// Input GEMM (fp16x3 MFMA): pre[b,j] = X[b,:].Wp[j,:] + bp[j]   (round-7 exact)
// grid (B/128, 4), block 256 (4 waves). Wave: 32 batch rows (bt=2) x 96 cols.
__global__ __launch_bounds__(256, 2) void gemm_in_mfma(
        const float* __restrict__ X, const _Float16* __restrict__ Wphi,
        const _Float16* __restrict__ Wplo, const float* __restrict__ bp,
        float* __restrict__ pre) {
    int tid = threadIdx.x;
    int w = tid >> 6, l = tid & 63, lr = l & 15, lq = l >> 4;
    int b0 = blockIdx.x * 128 + w * 32;
    int n0 = blockIdx.y * 96;
    const float* xrow0 = X + (size_t)(b0 + lr) * NIN;
    const float* xrow1 = X + (size_t)(b0 + 16 + lr) * NIN;
    f32x4 acc[6][2], acr[6][2];
    #pragma unroll
    for (int ct = 0; ct < 6; ++ct)
        #pragma unroll
        for (int bt = 0; bt < 2; ++bt)
            #pragma unroll
            for (int r = 0; r < 4; ++r) { acc[ct][bt][r] = 0.f; acr[ct][bt][r] = 0.f; }
    for (int kc = 0; kc < 24; ++kc) {
        int k0 = kc * 32 + lq * 8;
        f16x8 ahi[2], alo[2];
        {
            float4 x0 = *(const float4*)(xrow0 + k0);
            float4 x1 = *(const float4*)(xrow0 + k0 + 4);
            float xv[8] = { x0.x, x0.y, x0.z, x0.w, x1.x, x1.y, x1.z, x1.w };
            #pragma unroll
            for (int j = 0; j < 8; ++j) {
                _Float16 h = (_Float16)xv[j];
                ahi[0][j] = h;
                alo[0][j] = (_Float16)((xv[j] - (float)h) * LOSCALE);
            }
            float4 y0 = *(const float4*)(xrow1 + k0);
            float4 y1 = *(const float4*)(xrow1 + k0 + 4);
            float yv[8] = { y0.x, y0.y, y0.z, y0.w, y1.x, y1.y, y1.z, y1.w };
            #pragma unroll
            for (int j = 0; j < 8; ++j) {
                _Float16 h = (_Float16)yv[j];
                ahi[1][j] = h;
                alo[1][j] = (_Float16)((yv[j] - (float)h) * LOSCALE);
            }
        }
        #pragma unroll
        for (int ct = 0; ct < 6; ++ct) {
            size_t off = (size_t)(n0 + ct * 16 + lr) * NIN + k0;
            f16x8 bhi = *(const f16x8*)(Wphi + off);
            f16x8 blo = *(const f16x8*)(Wplo + off);
            #pragma unroll
            for (int bt = 0; bt < 2; ++bt) {
                acc[ct][bt] = __builtin_amdgcn_mfma_f32_16x16x32_f16(ahi[bt], bhi, acc[ct][bt], 0, 0, 0);
                acr[ct][bt] = __builtin_amdgcn_mfma_f32_16x16x32_f16(ahi[bt], blo, acr[ct][bt], 0, 0, 0);
                acr[ct][bt] = __builtin_amdgcn_mfma_f32_16x16x32_f16(alo[bt], bhi, acr[ct][bt], 0, 0, 0);
            }
        }
    }
    {   // K tail 768..783 (16 valid): lanes lq>=2 contribute zeros
        f16x8 ahi[2], alo[2];
        #pragma unroll
        for (int bt = 0; bt < 2; ++bt)
            #pragma unroll
            for (int j = 0; j < 8; ++j) { ahi[bt][j] = (_Float16)0.f; alo[bt][j] = (_Float16)0.f; }
        if (lq < 2) {
            const float* xr[2] = { xrow0, xrow1 };
            #pragma unroll
            for (int bt = 0; bt < 2; ++bt) {
                float4 x0 = *(const float4*)(xr[bt] + 768 + lq * 8);
                float4 x1 = *(const float4*)(xr[bt] + 768 + lq * 8 + 4);
                float xv[8] = { x0.x, x0.y, x0.z, x0.w, x1.x, x1.y, x1.z, x1.w };
                #pragma unroll
                for (int j = 0; j < 8; ++j) {
                    _Float16 h = (_Float16)xv[j];
                    ahi[bt][j] = h;
                    alo[bt][j] = (_Float16)((xv[j] - (float)h) * LOSCALE);
                }
            }
        }
        #pragma unroll
        for (int ct = 0; ct < 6; ++ct) {
            f16x8 bhi, blo;
            #pragma unroll
            for (int j = 0; j < 8; ++j) { bhi[j] = (_Float16)0.f; blo[j] = (_Float16)0.f; }
            if (lq < 2) {
                size_t off = (size_t)(n0 + ct * 16 + lr) * NIN + 768 + lq * 8;
                bhi = *(const f16x8*)(Wphi + off);
                blo = *(const f16x8*)(Wplo + off);
            }
            #pragma unroll
            for (int bt = 0; bt < 2; ++bt) {
                acc[ct][bt] = __builtin_amdgcn_mfma_f32_16x16x32_f16(ahi[bt], bhi, acc[ct][bt], 0, 0, 0);
                acr[ct][bt] = __builtin_amdgcn_mfma_f32_16x16x32_f16(ahi[bt], blo, acr[ct][bt], 0, 0, 0);
                acr[ct][bt] = __builtin_amdgcn_mfma_f32_16x16x32_f16(alo[bt], bhi, acr[ct][bt], 0, 0, 0);
            }
        }
    }
    #pragma unroll
    for (int ct = 0; ct < 6; ++ct) {
        int n = n0 + ct * 16 + lr;
        float bias = bp[n];
        #pragma unroll
        for (int bt = 0; bt < 2; ++bt) {
            int brow = b0 + bt * 16 + lq * 4;
            #pragma unroll
            for (int r = 0; r < 4; ++r)
                pre[(size_t)(brow + r) * NH + n] = acc[ct][bt][r] + LOINV * acr[ct][bt][r] + bias;
        }
    }
}

// ---------------------------------------------------------------------------
// Normalize + hi/lo split (used for the last layer only): y = a*relu(pre)+c
__global__ __launch_bounds__(256) void norm_hl(
        const float* __restrict__ pre, const float* __restrict__ a,
        const float* __restrict__ c, _Float16* __restrict__ hi,
        _Float16* __restrict__ lo) {
    int idx = blockIdx.x * 256 + threadIdx.x;   // over B*NH/8
    int j = (idx * 8) % NH;
    float4 v0 = ((const float4*)pre)[idx * 2];
    float4 v1 = ((const float4*)pre)[idx * 2 + 1];
    float y[8] = {
        a[j+0] * fmaxf(v0.x, 0.f) + c[j+0], a[j+1] * fmaxf(v0.y, 0.f) + c[j+1],
        a[j+2] * fmaxf(v0.z, 0.f) + c[j+2], a[j+3] * fmaxf(v0.w, 0.f) + c[j+3],
        a[j+4] * fmaxf(v1.x, 0.f) + c[j+4], a[j+5] * fmaxf(v1.y, 0.f) + c[j+5],
        a[j+6] * fmaxf(v1.z, 0.f) + c[j+6], a[j+7] * fmaxf(v1.w, 0.f) + c[j+7] };
    f16x8 h8, l8;
    #pragma unroll
    for (int jj = 0; jj < 8; ++jj) {
        _Float16 h = (_Float16)y[jj];
        h8[jj] = h;
        l8[jj] = (_Float16)((y[jj] - (float)h) * LOSCALE);
    }
    *(f16x8*)(hi + (size_t)idx * 8) = h8;
    *(f16x8*)(lo + (size_t)idx * 8) = l8;
}

// ---------------------------------------------------------------------------
// Fused norm + gate GEMM (round-9 version, kept: saved ~90 µs).
// grid B/64, block 256 (4 waves); wave: 48 st-rows x 16 b-cols.
__global__ __launch_bounds__(256, 2) void normgate_mfma(
        const float* __restrict__ pre, const float* __restrict__ a,
        const float* __restrict__ c, const _Float16* __restrict__ WgHi,
        const _Float16* __restrict__ WgLo, _Float16* __restrict__ aHi,
        _Float16* __restrict__ aLo, float* __restrict__ gateT,
        float* __restrict__ tg, int firstLayer) {
    int tid = threadIdx.x;
    int w = tid >> 6, l = tid & 63, lr = l & 15, lq = l >> 4;
    int b = blockIdx.x * 64 + w * 16 + lr;
    const float* prow = pre + (size_t)b * NH;
    f32x4 acc[3], acr[3];
    #pragma unroll
    for (int rt = 0; rt < 3; ++rt)
        #pragma unroll
        for (int r = 0; r < 4; ++r) { acc[rt][r] = 0.f; acr[rt][r] = 0.f; }
    #pragma unroll
    for (int kc = 0; kc < 12; ++kc) {
        int k0 = kc * 32 + lq * 8;
        float4 v0 = *(const float4*)(prow + k0);
        float4 v1 = *(const float4*)(prow + k0 + 4);
        float4 a0 = *(const float4*)(a + k0);
        float4 a1 = *(const float4*)(a + k0 + 4);
        float4 c0 = *(const float4*)(c + k0);
        float4 c1 = *(const float4*)(c + k0 + 4);
        float y[8] = {
            a0.x * fmaxf(v0.x, 0.f) + c0.x, a0.y * fmaxf(v0.y, 0.f) + c0.y,
            a0.z * fmaxf(v0.z, 0.f) + c0.z, a0.w * fmaxf(v0.w, 0.f) + c0.w,
            a1.x * fmaxf(v1.x, 0.f) + c1.x, a1.y * fmaxf(v1.y, 0.f) + c1.y,
            a1.z * fmaxf(v1.z, 0.f) + c1.z, a1.w * fmaxf(v1.w, 0.f) + c1.w };
        f16x8 bhi, blo;
        #pragma unroll
        for (int j = 0; j < 8; ++j) {
            _Float16 h = (_Float16)y[j];
            bhi[j] = h;
            blo[j] = (_Float16)((y[j] - (float)h) * LOSCALE);
        }
        *(f16x8*)(aHi + (size_t)b * NH + k0) = bhi;
        *(f16x8*)(aLo + (size_t)b * NH + k0) = blo;
        #pragma unroll
        for (int rt = 0; rt < 3; ++rt) {
            size_t off = (size_t)(rt * 16 + lr) * NH + k0;
            f16x8 whi = *(const f16x8*)(WgHi + off);
            f16x8 wlo = *(const f16x8*)(WgLo + off);
            acc[rt] = __builtin_amdgcn_mfma_f32_16x16x32_f16(whi, bhi, acc[rt], 0, 0, 0);
            acr[rt] = __builtin_amdgcn_mfma_f32_16x16x32_f16(whi, blo, acr[rt], 0, 0, 0);
            acr[rt] = __builtin_amdgcn_mfma_f32_16x16x32_f16(wlo, bhi, acr[rt], 0, 0, 0);
        }
    }
    float gsum = 0.f;
    #pragma unroll
    for (int rt = 0; rt < 3; ++rt)
        #pragma unroll
        for (int r = 0; r < 4; ++r) {
            int st = rt * 16 + lq * 4 + r;
            if (st < 36) {
                float p = acc[rt][r] + LOINV * acr[rt][r];
                float g = fminf(fmaxf(p, 0.f), 1.f);
                gateT[(size_t)st * BATCH + b] = g;
                gsum += g;
            }
        }
    gsum += __shfl_xor(gsum, 16, 64);
    gsum += __shfl_xor(gsum, 32, 64);
    if (lq == 0) tg[b] = (firstLayer ? 0.f : tg[b]) + gsum;
}

// ---------------------------------------------------------------------------
// Routed layer (fp16x3 MFMA, transposed D^T[e][b]).  ROUND-7 EXACT (known
// non-spilling codegen: ~55 us/dispatch).  grid (B/64, 2), block 256.
// Block: 64 batch rows (ct=4), targets t0..t0+2 (t0 = blockIdx.y*3).
__global__ __launch_bounds__(256, 2) void layer_data_mfma(
        const _Float16* __restrict__ aHi, const _Float16* __restrict__ aLo,
        const float* __restrict__ gateT, const _Float16* __restrict__ Wdhi,
        const _Float16* __restrict__ Wdlo, const float* __restrict__ bd_l,
        float* __restrict__ pre) {
    int tid = threadIdx.x;
    int w = tid >> 6, l = tid & 63, lr = l & 15, lq = l >> 4;
    int b0 = blockIdx.x * 64;
    int t0 = blockIdx.y * 3;
    int e0 = w * 16;
    f32x4 acc[3][4];
    #pragma unroll
    for (int t = 0; t < 3; ++t)
        #pragma unroll
        for (int ct = 0; ct < 4; ++ct)
            #pragma unroll
            for (int r = 0; r < 4; ++r) acc[t][ct][r] = 0.f;
    for (int s = 0; s < 6; ++s) {
        f16x8 bhi[4][2], blo[4][2];   // [ct][ks]
        #pragma unroll
        for (int ct = 0; ct < 4; ++ct) {
            size_t arow = (size_t)(b0 + ct * 16 + lr) * NH + s * 64 + lq * 8;
            #pragma unroll
            for (int ks = 0; ks < 2; ++ks) {
                bhi[ct][ks] = *(const f16x8*)(aHi + arow + ks * 32);
                blo[ct][ks] = *(const f16x8*)(aLo + arow + ks * 32);
            }
        }
        #pragma unroll
        for (int tt = 0; tt < 3; ++tt) {
            int t = t0 + tt;
            float g[4];
            #pragma unroll
            for (int ct = 0; ct < 4; ++ct)
                g[ct] = gateT[(size_t)(s * 6 + t) * BATCH + b0 + ct * 16 + lr];
            size_t wb = ((size_t)(s * 6 + t) * 64 + e0 + lr) * 64 + lq * 8;
            f16x8 ah0 = *(const f16x8*)(Wdhi + wb);
            f16x8 ah1 = *(const f16x8*)(Wdhi + wb + 32);
            f16x8 al0 = *(const f16x8*)(Wdlo + wb);
            f16x8 al1 = *(const f16x8*)(Wdlo + wb + 32);
            float bdv[4];
            #pragma unroll
            for (int r = 0; r < 4; ++r)
                bdv[r] = bd_l[(s * 6 + t) * 64 + e0 + lq * 4 + r];
            #pragma unroll
            for (int ct = 0; ct < 4; ++ct) {
                f32x4 ph, pc;
                #pragma unroll
                for (int r = 0; r < 4; ++r) { ph[r] = 0.f; pc[r] = 0.f; }
                ph = __builtin_amdgcn_mfma_f32_16x16x32_f16(ah0, bhi[ct][0], ph, 0, 0, 0);
                ph = __builtin_amdgcn_mfma_f32_16x16x32_f16(ah1, bhi[ct][1], ph, 0, 0, 0);
                pc = __builtin_amdgcn_mfma_f32_16x16x32_f16(ah0, blo[ct][0], pc, 0, 0, 0);
                pc = __builtin_amdgcn_mfma_f32_16x16x32_f16(ah1, blo[ct][1], pc, 0, 0, 0);
                pc = __builtin_amdgcn_mfma_f32_16x16x32_f16(al0, bhi[ct][0], pc, 0, 0, 0);
                pc = __builtin_amdgcn_mfma_f32_16x16x32_f16(al1, bhi[ct][1], pc, 0, 0, 0);
                #pragma unroll
                for (int r = 0; r < 4; ++r)
                    acc[tt][ct][r] += g[ct] * (ph[r] + LOINV * pc[r] + bdv[r]);
            }
        }
    }
    #pragma unroll
    for (int tt = 0; tt < 3; ++tt)
        #pragma unroll
        for (int ct = 0; ct < 4; ++ct)
            #pragma unroll
            for (int r = 0; r < 4; ++r)
                pre[(size_t)(b0 + ct * 16 + lr) * NH + (t0 + tt) * 64 + e0 + lq * 4 + r]
                    = acc[tt][ct][r];
}

// ---------------------------------------------------------------------------
// Output head GEMM (fp16x3 MFMA) + tg copy.
__global__ __launch_bounds__(256, 2) void out_mfma(
        const _Float16* __restrict__ aHi, const _Float16* __restrict__ aLo,
        const _Float16* __restrict__ OutHi, const _Float16* __restrict__ OutLo,
        const float* __restrict__ tg, float* __restrict__ dout) {
    int tid = threadIdx.x;
    int w = tid >> 6, l = tid & 63, lr = l & 15, lq = l >> 4;
    int b = blockIdx.x * 64 + w * 16 + lr;
    const _Float16* arowH = aHi + (size_t)b * NH;
    const _Float16* arowL = aLo + (size_t)b * NH;
    f32x4 acc, acr;
    #pragma unroll
    for (int r = 0; r < 4; ++r) { acc[r] = 0.f; acr[r] = 0.f; }
    #pragma unroll
    for (int kc = 0; kc < 12; ++kc) {
        int k0 = kc * 32 + lq * 8;
        f16x8 bhi = *(const f16x8*)(arowH + k0);
        f16x8 blo = *(const f16x8*)(arowL + k0);
        size_t off = (size_t)lr * NH + k0;
        f16x8 ahi = *(const f16x8*)(OutHi + off);
        f16x8 alo = *(const f16x8*)(OutLo + off);
        acc = __builtin_amdgcn_mfma_f32_16x16x32_f16(ahi, bhi, acc, 0, 0, 0);
        acr = __builtin_amdgcn_mfma_f32_16x16x32_f16(ahi, blo, acr, 0, 0, 0);
        acr = __builtin_amdgcn_mfma_f32_16x16x32_f16(alo, bhi, acr, 0, 0, 0);
    }
    #pragma unroll
    for (int r = 0; r < 4; ++r) {
        int o = lq * 4 + r;
        if (o < NOUT)
            dout[(size_t)b * NOUT + o] = acc[r] + LOINV * acr[r];
    }
    if (lq == 0) dout[(size_t)BATCH * NOUT + b] = tg[b];
}

// ---------------------------------------------------------------------------
extern "C" void kernel_launch(void* const* d_in, const int* in_sizes, int n_in,
                              void* d_out, int out_size, void* d_ws, size_t ws_size,
                              hipStream_t stream) {
    const float* x        = (const float*)d_in[0];
    const float* gamma_in = (const float*)d_in[1];
    const float* beta_in  = (const float*)d_in[2];
    const float* W_in     = (const float*)d_in[3];
    const float* b_in     = (const float*)d_in[4];
    const float* Wg       = (const float*)d_in[5];
    const float* Wd       = (const float*)d_in[6];
    const float* bd       = (const float*)d_in[7];
    const float* gamma_h  = (const float*)d_in[8];
    const float* beta_h   = (const float*)d_in[9];
    const float* W_out    = (const float*)d_in[10];
    float* dout = (float*)d_out;
    float* ws = (float*)d_ws;

    // workspace layout (float offsets), total ~14.59M floats = 58.4 MiB
    float* psum  = ws;                              // 128*1024
    float* psq   = ws + 131072;                     // 128*1024
    float* avec  = ws + 262144;                     // 1024
    float* cvec  = ws + 263168;                     // 1024
    float* bp    = ws + 264192;                     // 1024
    float* pre   = ws + 265216;                     // B*NH f32
    _Float16* actsHi = (_Float16*)(ws + 6556672);   // B*NH f16
    _Float16* actsLo = (_Float16*)(ws + 9702400);   // B*NH f16
    float* gateT = ws + 12848128;                   // 36*B f32
    float* tg    = ws + 13437952;                   // B
    _Float16* WpHi = (_Float16*)(ws + 13454336);    // 384*784 f16
    _Float16* WpLo = (_Float16*)(ws + 13604864);    // 384*784 f16
    _Float16* WdHiAll = (_Float16*)(ws + 13755392); // 5*36*4096 f16
    _Float16* WdLoAll = (_Float16*)(ws + 14124032); // 5*36*4096 f16
    _Float16* WgHiAll = (_Float16*)(ws + 14492672); // 5*48*384 f16
    _Float16* WgLoAll = (_Float16*)(ws + 14538752); // 5*48*384 f16
    _Float16* OutHi   = (_Float16*)(ws + 14584832); // 16*384 f16
    _Float16* OutLo   = (_Float16*)(ws + 14587904); // 16*384 f16

    dim3 blk(256);

    // ---- prep: input BN fold + all weight split-casts (up front)
    stats_partial<<<dim3(4, NPART), blk, 0, stream>>>(x, NIN, 0, psum, psq);
    stats_finalize<<<dim3(4), blk, 0, stream>>>(psum, psq, NIN, gamma_in, beta_in, avec, cvec);
    scale_win_hl<<<dim3((NH * NIN / 4 + 255) / 256), blk, 0, stream>>>(W_in, avec, WpHi, WpLo);
    bias_in<<<dim3(NH), dim3(64), 0, stream>>>(W_in, b_in, cvec, bp);
    conv_hl<<<dim3((5 * 36 * 4096 / 4 + 255) / 256), blk, 0, stream>>>(
            Wd, WdHiAll, WdLoAll, 5 * 36 * 4096 / 4);
    prep_wg<<<dim3((5 * 48 * 384 + 255) / 256), blk, 0, stream>>>(Wg, WgHiAll, WgLoAll);
    prep_wout<<<dim3((16 * 384 + 255) / 256), blk, 0, stream>>>(W_out, OutHi, OutLo);

    // ---- input GEMM (fp16x3 MFMA) -> pre f32
    gemm_in_mfma<<<dim3(BATCH / 128, 4), blk, 0, stream>>>(x, WpHi, WpLo, bp, pre);

    // ---- hidden layers
    for (int j = 0; j < NLAYERS; ++j) {
        stats_partial<<<dim3(2, NPART), blk, 0, stream>>>(pre, NH, 1, psum, psq);
        stats_finalize<<<dim3(2), blk, 0, stream>>>(psum, psq, NH,
                gamma_h + j * NH, beta_h + j * NH, avec, cvec);
        if (j < NLAYERS - 1) {
            int l = j;
            normgate_mfma<<<dim3(BATCH / 64), blk, 0, stream>>>(
                    pre, avec, cvec, WgHiAll + (size_t)l * 48 * 384,
                    WgLoAll + (size_t)l * 48 * 384, actsHi, actsLo, gateT, tg, l == 0);
            layer_data_mfma<<<dim3(BATCH / 64, 2), blk, 0, stream>>>(
                    actsHi, actsLo, gateT, WdHiAll + (size_t)l * 36 * 4096,
                    WdLoAll + (size_t)l * 36 * 4096, bd + (size_t)l * 36 * 64, pre);
        } else {
            norm_hl<<<dim3(BATCH * NH / 8 / 256), blk, 0, stream>>>(
                    pre, avec, cvec, actsHi, actsLo);
        }
    }

    // ---- output head + total_gate
    out_mfma<<<dim3(BATCH / 64), blk, 0, stream>>>(actsHi, actsLo, OutHi, OutLo, tg, dout);
}

// Round 11
// 571.061 us; speedup vs baseline: 2.9330x; 1.0641x over previous
//
#include <hip/hip_runtime.h>
#include <hip/hip_bf16.h>

#define BATCH   16384
#define NIN     784
#define NH      384
#define NLAYERS 6
#define NOUT    10
#define EPS_BN  1e-5f
#define LOSCALE 2048.0f
#define LOINV   (1.0f/2048.0f)
#define NPART   128
#define PSTRIDE 1024

typedef __attribute__((ext_vector_type(8))) _Float16 f16x8;
typedef __attribute__((ext_vector_type(4))) _Float16 f16x4;
typedef __attribute__((ext_vector_type(4))) float f32x4;

// ---------------------------------------------------------------------------
// Column stats (two-stage, deterministic).  src [B, C] f32 row-major.
__global__ __launch_bounds__(256) void stats_partial(
        const float* __restrict__ src, int C, int applyRelu,
        float* __restrict__ psum, float* __restrict__ psq) {
    int c = blockIdx.x * 256 + threadIdx.x;
    if (c >= C) return;
    int r0 = blockIdx.y * (BATCH / NPART);
    float s = 0.f, q = 0.f;
    for (int r = r0; r < r0 + BATCH / NPART; ++r) {
        float v = src[(size_t)r * C + c];
        if (applyRelu) v = fmaxf(v, 0.f);
        s += v; q += v * v;
    }
    psum[blockIdx.y * PSTRIDE + c] = s;
    psq [blockIdx.y * PSTRIDE + c] = q;
}

__global__ __launch_bounds__(256) void stats_finalize(
        const float* __restrict__ psum, const float* __restrict__ psq, int C,
        const float* __restrict__ gamma, const float* __restrict__ beta,
        float* __restrict__ a_out, float* __restrict__ c_out) {
    int c = blockIdx.x * 256 + threadIdx.x;
    if (c >= C) return;
    float s = 0.f, q = 0.f;
    for (int i = 0; i < NPART; ++i) { s += psum[i * PSTRIDE + c]; q += psq[i * PSTRIDE + c]; }
    const float invB = 1.f / (float)BATCH;
    float mu  = s * invB;
    float var = q * invB - mu * mu;
    float rs  = rsqrtf(var + EPS_BN);
    float g   = gamma[c];
    a_out[c] = g * rs;
    c_out[c] = beta[c] - g * mu * rs;
}

// ---------------------------------------------------------------------------
// Wp[j][n] = a[n]*W_in[j][n] split into f16 hi/lo(scaled).  4 elems/thread.
__global__ __launch_bounds__(256) void scale_win_hl(
        const float* __restrict__ W_in, const float* __restrict__ a,
        _Float16* __restrict__ whi, _Float16* __restrict__ wlo) {
    int i = blockIdx.x * 256 + threadIdx.x;
    if (i >= NH * NIN / 4) return;
    int n = (i * 4) % NIN;
    float4 wv = ((const float4*)W_in)[i];
    float v[4] = { wv.x * a[n], wv.y * a[n + 1], wv.z * a[n + 2], wv.w * a[n + 3] };
    f16x4 h4, l4;
    #pragma unroll
    for (int j = 0; j < 4; ++j) {
        _Float16 h = (_Float16)v[j];
        h4[j] = h;
        l4[j] = (_Float16)((v[j] - (float)h) * LOSCALE);
    }
    *(f16x4*)(whi + (size_t)i * 4) = h4;
    *(f16x4*)(wlo + (size_t)i * 4) = l4;
}

// f32 -> f16 hi/lo(scaled) split, 4 elems/thread (all Wd layers at once)
__global__ __launch_bounds__(256) void conv_hl(
        const float* __restrict__ src, _Float16* __restrict__ hi,
        _Float16* __restrict__ lo, int n4) {
    int i = blockIdx.x * 256 + threadIdx.x;
    if (i >= n4) return;
    float4 wv = ((const float4*)src)[i];
    float v[4] = { wv.x, wv.y, wv.z, wv.w };
    f16x4 h4, l4;
    #pragma unroll
    for (int j = 0; j < 4; ++j) {
        _Float16 h = (_Float16)v[j];
        h4[j] = h;
        l4[j] = (_Float16)((v[j] - (float)h) * LOSCALE);
    }
    *(f16x4*)(hi + (size_t)i * 4) = h4;
    *(f16x4*)(lo + (size_t)i * 4) = l4;
}

// Zero-padded gate weights: WgPad[l][st][k] (48 rows, 384 cols)
__global__ __launch_bounds__(256) void prep_wg(
        const float* __restrict__ Wg, _Float16* __restrict__ hi,
        _Float16* __restrict__ lo) {
    int idx = blockIdx.x * 256 + threadIdx.x;
    if (idx >= 5 * 48 * 384) return;
    int l = idx / (48 * 384);
    int r = idx % (48 * 384);
    int st = r / 384, k = r % 384;
    float v = 0.f;
    if (st < 36 && (k >> 6) == st / 6)
        v = Wg[l * 36 * 64 + st * 64 + (k & 63)];
    _Float16 h = (_Float16)v;
    hi[idx] = h;
    lo[idx] = (_Float16)((v - (float)h) * LOSCALE);
}

// Padded output weights: OutPad[o][k] (16 rows x 384)
__global__ __launch_bounds__(256) void prep_wout(
        const float* __restrict__ W_out, _Float16* __restrict__ hi,
        _Float16* __restrict__ lo) {
    int idx = blockIdx.x * 256 + threadIdx.x;
    if (idx >= 16 * 384) return;
    int o = idx / 384, k = idx % 384;
    float v = 0.f;
    if (o < NOUT) v = W_out[((k >> 6) * NOUT + o) * 64 + (k & 63)];
    _Float16 h = (_Float16)v;
    hi[idx] = h;
    lo[idx] = (_Float16)((v - (float)h) * LOSCALE);
}

// b'[j] = b_in[j] + sum_n c[n]*W_in[j,n]  (f32, exact)
__global__ __launch_bounds__(64) void bias_in(
        const float* __restrict__ W_in, const float* __restrict__ b_in,
        const float* __restrict__ cvec, float* __restrict__ bp) {
    int j = blockIdx.x;
    int lane = threadIdx.x;
    float s = 0.f;
    for (int n = lane; n < NIN; n += 64) s += cvec[n] * W_in[j * NIN + n];
    #pragma unroll
    for (int m = 1; m < 64; m <<= 1) s += __shfl_xor(s, m, 64);
    if (lane == 0) bp[j] = b_in[j] + s;
}

// ---------------------------------------------------------------------------
// Input GEMM (fp16x3 MFMA): pre[b,j] = X[b,:].Wp[j,:] + bp[j]
// grid (B/128, 6), block 256 (4 waves). Wave: 32 batch rows (bt=2) x 64 cols.
__global__ __launch_bounds__(256, 2) void gemm_in_mfma(
        const float* __restrict__ X, const _Float16* __restrict__ Wphi,
        const _Float16* __restrict__ Wplo, const float* __restrict__ bp,
        float* __restrict__ pre) {
    int tid = threadIdx.x;
    int w = tid >> 6, l = tid & 63, lr = l & 15, lq = l >> 4;
    int b0 = blockIdx.x * 128 + w * 32;
    int n0 = blockIdx.y * 64;
    const float* xrow0 = X + (size_t)(b0 + lr) * NIN;
    const float* xrow1 = X + (size_t)(b0 + 16 + lr) * NIN;
    f32x4 acc[4][2], acr[4][2];
    #pragma unroll
    for (int ct = 0; ct < 4; ++ct)
        #pragma unroll
        for (int bt = 0; bt < 2; ++bt)
            #pragma unroll
            for (int r = 0; r < 4; ++r) { acc[ct][bt][r] = 0.f; acr[ct][bt][r] = 0.f; }
    for (int kc = 0; kc < 24; ++kc) {
        int k0 = kc * 32 + lq * 8;
        f16x8 ahi[2], alo[2];
        {
            float4 x0 = *(const float4*)(xrow0 + k0);
            float4 x1 = *(const float4*)(xrow0 + k0 + 4);
            float xv[8] = { x0.x, x0.y, x0.z, x0.w, x1.x, x1.y, x1.z, x1.w };
            #pragma unroll
            for (int j = 0; j < 8; ++j) {
                _Float16 h = (_Float16)xv[j];
                ahi[0][j] = h;
                alo[0][j] = (_Float16)((xv[j] - (float)h) * LOSCALE);
            }
            float4 y0 = *(const float4*)(xrow1 + k0);
            float4 y1 = *(const float4*)(xrow1 + k0 + 4);
            float yv[8] = { y0.x, y0.y, y0.z, y0.w, y1.x, y1.y, y1.z, y1.w };
            #pragma unroll
            for (int j = 0; j < 8; ++j) {
                _Float16 h = (_Float16)yv[j];
                ahi[1][j] = h;
                alo[1][j] = (_Float16)((yv[j] - (float)h) * LOSCALE);
            }
        }
        #pragma unroll
        for (int ct = 0; ct < 4; ++ct) {
            size_t off = (size_t)(n0 + ct * 16 + lr) * NIN + k0;
            f16x8 bhi = *(const f16x8*)(Wphi + off);
            f16x8 blo = *(const f16x8*)(Wplo + off);
            #pragma unroll
            for (int bt = 0; bt < 2; ++bt) {
                acc[ct][bt] = __builtin_amdgcn_mfma_f32_16x16x32_f16(ahi[bt], bhi, acc[ct][bt], 0, 0, 0);
                acr[ct][bt] = __builtin_amdgcn_mfma_f32_16x16x32_f16(ahi[bt], blo, acr[ct][bt], 0, 0, 0);
                acr[ct][bt] = __builtin_amdgcn_mfma_f32_16x16x32_f16(alo[bt], bhi, acr[ct][bt], 0, 0, 0);
            }
        }
    }
    {   // K tail 768..783 (16 valid): lanes lq>=2 contribute zeros
        f16x8 ahi[2], alo[2];
        #pragma unroll
        for (int bt = 0; bt < 2; ++bt)
            #pragma unroll
            for (int j = 0; j < 8; ++j) { ahi[bt][j] = (_Float16)0.f; alo[bt][j] = (_Float16)0.f; }
        if (lq < 2) {
            const float* xr[2] = { xrow0, xrow1 };
            #pragma unroll
            for (int bt = 0; bt < 2; ++bt) {
                float4 x0 = *(const float4*)(xr[bt] + 768 + lq * 8);
                float4 x1 = *(const float4*)(xr[bt] + 768 + lq * 8 + 4);
                float xv[8] = { x0.x, x0.y, x0.z, x0.w, x1.x, x1.y, x1.z, x1.w };
                #pragma unroll
                for (int j = 0; j < 8; ++j) {
                    _Float16 h = (_Float16)xv[j];
                    ahi[bt][j] = h;
                    alo[bt][j] = (_Float16)((xv[j] - (float)h) * LOSCALE);
                }
            }
        }
        #pragma unroll
        for (int ct = 0; ct < 4; ++ct) {
            f16x8 bhi, blo;
            #pragma unroll
            for (int j = 0; j < 8; ++j) { bhi[j] = (_Float16)0.f; blo[j] = (_Float16)0.f; }
            if (lq < 2) {
                size_t off = (size_t)(n0 + ct * 16 + lr) * NIN + 768 + lq * 8;
                bhi = *(const f16x8*)(Wphi + off);
                blo = *(const f16x8*)(Wplo + off);
            }
            #pragma unroll
            for (int bt = 0; bt < 2; ++bt) {
                acc[ct][bt] = __builtin_amdgcn_mfma_f32_16x16x32_f16(ahi[bt], bhi, acc[ct][bt], 0, 0, 0);
                acr[ct][bt] = __builtin_amdgcn_mfma_f32_16x16x32_f16(ahi[bt], blo, acr[ct][bt], 0, 0, 0);
                acr[ct][bt] = __builtin_amdgcn_mfma_f32_16x16x32_f16(alo[bt], bhi, acr[ct][bt], 0, 0, 0);
            }
        }
    }
    #pragma unroll
    for (int ct = 0; ct < 4; ++ct) {
        int n = n0 + ct * 16 + lr;
        float bias = bp[n];
        #pragma unroll
        for (int bt = 0; bt < 2; ++bt) {
            int brow = b0 + bt * 16 + lq * 4;
            #pragma unroll
            for (int r = 0; r < 4; ++r)
                pre[(size_t)(brow + r) * NH + n] = acc[ct][bt][r] + LOINV * acr[ct][bt][r] + bias;
        }
    }
}

// ---------------------------------------------------------------------------
// Fused norm + gate GEMM, K-SPLIT across 4 waves for occupancy.
// grid (B/16), block 256 (4 waves, all on the same 16 batch rows).  Wave kw
// handles kc in [3kw, 3kw+3): norms its K-chunk (writing actsHi/Lo once) and
// accumulates partial gate products; LDS-reduce; wave 0 does clip/gsum/tg.
__global__ __launch_bounds__(256, 2) void normgate_mfma(
        const float* __restrict__ pre, const float* __restrict__ a,
        const float* __restrict__ c, const _Float16* __restrict__ WgHi,
        const _Float16* __restrict__ WgLo, _Float16* __restrict__ aHi,
        _Float16* __restrict__ aLo, float* __restrict__ gateT,
        float* __restrict__ tg, int firstLayer) {
    __shared__ float red[24][3][64];   // [acc-elem][wave-1][lane]
    int tid = threadIdx.x;
    int kw = tid >> 6, l = tid & 63, lr = l & 15, lq = l >> 4;
    int b = blockIdx.x * 16 + lr;
    const float* prow = pre + (size_t)b * NH;
    f32x4 acc[3], acr[3];
    #pragma unroll
    for (int rt = 0; rt < 3; ++rt)
        #pragma unroll
        for (int r = 0; r < 4; ++r) { acc[rt][r] = 0.f; acr[rt][r] = 0.f; }
    #pragma unroll
    for (int kk = 0; kk < 3; ++kk) {
        int k0 = (kw * 3 + kk) * 32 + lq * 8;
        float4 v0 = *(const float4*)(prow + k0);
        float4 v1 = *(const float4*)(prow + k0 + 4);
        float4 a0 = *(const float4*)(a + k0);
        float4 a1 = *(const float4*)(a + k0 + 4);
        float4 c0 = *(const float4*)(c + k0);
        float4 c1 = *(const float4*)(c + k0 + 4);
        float y[8] = {
            a0.x * fmaxf(v0.x, 0.f) + c0.x, a0.y * fmaxf(v0.y, 0.f) + c0.y,
            a0.z * fmaxf(v0.z, 0.f) + c0.z, a0.w * fmaxf(v0.w, 0.f) + c0.w,
            a1.x * fmaxf(v1.x, 0.f) + c1.x, a1.y * fmaxf(v1.y, 0.f) + c1.y,
            a1.z * fmaxf(v1.z, 0.f) + c1.z, a1.w * fmaxf(v1.w, 0.f) + c1.w };
        f16x8 bhi, blo;
        #pragma unroll
        for (int j = 0; j < 8; ++j) {
            _Float16 h = (_Float16)y[j];
            bhi[j] = h;
            blo[j] = (_Float16)((y[j] - (float)h) * LOSCALE);
        }
        *(f16x8*)(aHi + (size_t)b * NH + k0) = bhi;
        *(f16x8*)(aLo + (size_t)b * NH + k0) = blo;
        #pragma unroll
        for (int rt = 0; rt < 3; ++rt) {
            size_t off = (size_t)(rt * 16 + lr) * NH + k0;
            f16x8 whi = *(const f16x8*)(WgHi + off);
            f16x8 wlo = *(const f16x8*)(WgLo + off);
            acc[rt] = __builtin_amdgcn_mfma_f32_16x16x32_f16(whi, bhi, acc[rt], 0, 0, 0);
            acr[rt] = __builtin_amdgcn_mfma_f32_16x16x32_f16(whi, blo, acr[rt], 0, 0, 0);
            acr[rt] = __builtin_amdgcn_mfma_f32_16x16x32_f16(wlo, bhi, acr[rt], 0, 0, 0);
        }
    }
    if (kw > 0) {
        #pragma unroll
        for (int rt = 0; rt < 3; ++rt)
            #pragma unroll
            for (int r = 0; r < 4; ++r) {
                red[rt * 4 + r][kw - 1][l]      = acc[rt][r];
                red[12 + rt * 4 + r][kw - 1][l] = acr[rt][r];
            }
    }
    __syncthreads();
    if (kw == 0) {
        #pragma unroll
        for (int rt = 0; rt < 3; ++rt)
            #pragma unroll
            for (int r = 0; r < 4; ++r) {
                #pragma unroll
                for (int wv = 0; wv < 3; ++wv) {
                    acc[rt][r] += red[rt * 4 + r][wv][l];
                    acr[rt][r] += red[12 + rt * 4 + r][wv][l];
                }
            }
        float gsum = 0.f;
        #pragma unroll
        for (int rt = 0; rt < 3; ++rt)
            #pragma unroll
            for (int r = 0; r < 4; ++r) {
                int st = rt * 16 + lq * 4 + r;
                if (st < 36) {
                    float p = acc[rt][r] + LOINV * acr[rt][r];
                    float g = fminf(fmaxf(p, 0.f), 1.f);
                    gateT[(size_t)st * BATCH + b] = g;
                    gsum += g;
                }
            }
        gsum += __shfl_xor(gsum, 16, 64);
        gsum += __shfl_xor(gsum, 32, 64);
        if (lq == 0) tg[b] = (firstLayer ? 0.f : tg[b]) + gsum;
    }
}

// ---------------------------------------------------------------------------
// Routed layer (fp16x3 MFMA, transposed D^T[e][b]).  ROUND-7 EXACT (known
// non-spilling codegen).  grid (B/64, 2), block 256.
// Block: 64 batch rows (ct=4), targets t0..t0+2 (t0 = blockIdx.y*3).
__global__ __launch_bounds__(256, 2) void layer_data_mfma(
        const _Float16* __restrict__ aHi, const _Float16* __restrict__ aLo,
        const float* __restrict__ gateT, const _Float16* __restrict__ Wdhi,
        const _Float16* __restrict__ Wdlo, const float* __restrict__ bd_l,
        float* __restrict__ pre) {
    int tid = threadIdx.x;
    int w = tid >> 6, l = tid & 63, lr = l & 15, lq = l >> 4;
    int b0 = blockIdx.x * 64;
    int t0 = blockIdx.y * 3;
    int e0 = w * 16;
    f32x4 acc[3][4];
    #pragma unroll
    for (int t = 0; t < 3; ++t)
        #pragma unroll
        for (int ct = 0; ct < 4; ++ct)
            #pragma unroll
            for (int r = 0; r < 4; ++r) acc[t][ct][r] = 0.f;
    for (int s = 0; s < 6; ++s) {
        f16x8 bhi[4][2], blo[4][2];   // [ct][ks]
        #pragma unroll
        for (int ct = 0; ct < 4; ++ct) {
            size_t arow = (size_t)(b0 + ct * 16 + lr) * NH + s * 64 + lq * 8;
            #pragma unroll
            for (int ks = 0; ks < 2; ++ks) {
                bhi[ct][ks] = *(const f16x8*)(aHi + arow + ks * 32);
                blo[ct][ks] = *(const f16x8*)(aLo + arow + ks * 32);
            }
        }
        #pragma unroll
        for (int tt = 0; tt < 3; ++tt) {
            int t = t0 + tt;
            float g[4];
            #pragma unroll
            for (int ct = 0; ct < 4; ++ct)
                g[ct] = gateT[(size_t)(s * 6 + t) * BATCH + b0 + ct * 16 + lr];
            size_t wb = ((size_t)(s * 6 + t) * 64 + e0 + lr) * 64 + lq * 8;
            f16x8 ah0 = *(const f16x8*)(Wdhi + wb);
            f16x8 ah1 = *(const f16x8*)(Wdhi + wb + 32);
            f16x8 al0 = *(const f16x8*)(Wdlo + wb);
            f16x8 al1 = *(const f16x8*)(Wdlo + wb + 32);
            float bdv[4];
            #pragma unroll
            for (int r = 0; r < 4; ++r)
                bdv[r] = bd_l[(s * 6 + t) * 64 + e0 + lq * 4 + r];
            #pragma unroll
            for (int ct = 0; ct < 4; ++ct) {
                f32x4 ph, pc;
                #pragma unroll
                for (int r = 0; r < 4; ++r) { ph[r] = 0.f; pc[r] = 0.f; }
                ph = __builtin_amdgcn_mfma_f32_16x16x32_f16(ah0, bhi[ct][0], ph, 0, 0, 0);
                ph = __builtin_amdgcn_mfma_f32_16x16x32_f16(ah1, bhi[ct][1], ph, 0, 0, 0);
                pc = __builtin_amdgcn_mfma_f32_16x16x32_f16(ah0, blo[ct][0], pc, 0, 0, 0);
                pc = __builtin_amdgcn_mfma_f32_16x16x32_f16(ah1, blo[ct][1], pc, 0, 0, 0);
                pc = __builtin_amdgcn_mfma_f32_16x16x32_f16(al0, bhi[ct][0], pc, 0, 0, 0);
                pc = __builtin_amdgcn_mfma_f32_16x16x32_f16(al1, bhi[ct][1], pc, 0, 0, 0);
                #pragma unroll
                for (int r = 0; r < 4; ++r)
                    acc[tt][ct][r] += g[ct] * (ph[r] + LOINV * pc[r] + bdv[r]);
            }
        }
    }
    #pragma unroll
    for (int tt = 0; tt < 3; ++tt)
        #pragma unroll
        for (int ct = 0; ct < 4; ++ct)
            #pragma unroll
            for (int r = 0; r < 4; ++r)
                pre[(size_t)(b0 + ct * 16 + lr) * NH + (t0 + tt) * 64 + e0 + lq * 4 + r]
                    = acc[tt][ct][r];
}

// ---------------------------------------------------------------------------
// Fused last-layer norm + output head (K-split like normgate; no acts write).
// grid (B/16), block 256 (4 waves).  out[b,o<10] + tg copy.
__global__ __launch_bounds__(256, 2) void normout_mfma(
        const float* __restrict__ pre, const float* __restrict__ a,
        const float* __restrict__ c, const _Float16* __restrict__ OutHi,
        const _Float16* __restrict__ OutLo, const float* __restrict__ tg,
        float* __restrict__ dout) {
    __shared__ float red[8][3][64];
    int tid = threadIdx.x;
    int kw = tid >> 6, l = tid & 63, lr = l & 15, lq = l >> 4;
    int b = blockIdx.x * 16 + lr;
    const float* prow = pre + (size_t)b * NH;
    f32x4 acc, acr;
    #pragma unroll
    for (int r = 0; r < 4; ++r) { acc[r] = 0.f; acr[r] = 0.f; }
    #pragma unroll
    for (int kk = 0; kk < 3; ++kk) {
        int k0 = (kw * 3 + kk) * 32 + lq * 8;
        float4 v0 = *(const float4*)(prow + k0);
        float4 v1 = *(const float4*)(prow + k0 + 4);
        float4 a0 = *(const float4*)(a + k0);
        float4 a1 = *(const float4*)(a + k0 + 4);
        float4 c0 = *(const float4*)(c + k0);
        float4 c1 = *(const float4*)(c + k0 + 4);
        float y[8] = {
            a0.x * fmaxf(v0.x, 0.f) + c0.x, a0.y * fmaxf(v0.y, 0.f) + c0.y,
            a0.z * fmaxf(v0.z, 0.f) + c0.z, a0.w * fmaxf(v0.w, 0.f) + c0.w,
            a1.x * fmaxf(v1.x, 0.f) + c1.x, a1.y * fmaxf(v1.y, 0.f) + c1.y,
            a1.z * fmaxf(v1.z, 0.f) + c1.z, a1.w * fmaxf(v1.w, 0.f) + c1.w };
        f16x8 bhi, blo;
        #pragma unroll
        for (int j = 0; j < 8; ++j) {
            _Float16 h = (_Float16)y[j];
            bhi[j] = h;
            blo[j] = (_Float16)((y[j] - (float)h) * LOSCALE);
        }
        size_t off = (size_t)lr * NH + k0;
        f16x8 whi = *(const f16x8*)(OutHi + off);
        f16x8 wlo = *(const f16x8*)(OutLo + off);
        acc = __builtin_amdgcn_mfma_f32_16x16x32_f16(whi, bhi, acc, 0, 0, 0);
        acr = __builtin_amdgcn_mfma_f32_16x16x32_f16(whi, blo, acr, 0, 0, 0);
        acr = __builtin_amdgcn_mfma_f32_16x16x32_f16(wlo, bhi, acr, 0, 0, 0);
    }
    if (kw > 0) {
        #pragma unroll
        for (int r = 0; r < 4; ++r) {
            red[r][kw - 1][l]     = acc[r];
            red[4 + r][kw - 1][l] = acr[r];
        }
    }
    __syncthreads();
    if (kw == 0) {
        #pragma unroll
        for (int r = 0; r < 4; ++r)
            #pragma unroll
            for (int wv = 0; wv < 3; ++wv) {
                acc[r] += red[r][wv][l];
                acr[r] += red[4 + r][wv][l];
            }
        #pragma unroll
        for (int r = 0; r < 4; ++r) {
            int o = lq * 4 + r;
            if (o < NOUT)
                dout[(size_t)b * NOUT + o] = acc[r] + LOINV * acr[r];
        }
        if (lq == 0) dout[(size_t)BATCH * NOUT + b] = tg[b];
    }
}

// ---------------------------------------------------------------------------
extern "C" void kernel_launch(void* const* d_in, const int* in_sizes, int n_in,
                              void* d_out, int out_size, void* d_ws, size_t ws_size,
                              hipStream_t stream) {
    const float* x        = (const float*)d_in[0];
    const float* gamma_in = (const float*)d_in[1];
    const float* beta_in  = (const float*)d_in[2];
    const float* W_in     = (const float*)d_in[3];
    const float* b_in     = (const float*)d_in[4];
    const float* Wg       = (const float*)d_in[5];
    const float* Wd       = (const float*)d_in[6];
    const float* bd       = (const float*)d_in[7];
    const float* gamma_h  = (const float*)d_in[8];
    const float* beta_h   = (const float*)d_in[9];
    const float* W_out    = (const float*)d_in[10];
    float* dout = (float*)d_out;
    float* ws = (float*)d_ws;

    // workspace layout (float offsets), total ~14.59M floats = 58.4 MiB
    float* psum  = ws;                              // 128*1024
    float* psq   = ws + 131072;                     // 128*1024
    float* avec  = ws + 262144;                     // 1024
    float* cvec  = ws + 263168;                     // 1024
    float* bp    = ws + 264192;                     // 1024
    float* pre   = ws + 265216;                     // B*NH f32
    _Float16* actsHi = (_Float16*)(ws + 6556672);   // B*NH f16
    _Float16* actsLo = (_Float16*)(ws + 9702400);   // B*NH f16
    float* gateT = ws + 12848128;                   // 36*B f32
    float* tg    = ws + 13437952;                   // B
    _Float16* WpHi = (_Float16*)(ws + 13454336);    // 384*784 f16
    _Float16* WpLo = (_Float16*)(ws + 13604864);    // 384*784 f16
    _Float16* WdHiAll = (_Float16*)(ws + 13755392); // 5*36*4096 f16
    _Float16* WdLoAll = (_Float16*)(ws + 14124032); // 5*36*4096 f16
    _Float16* WgHiAll = (_Float16*)(ws + 14492672); // 5*48*384 f16
    _Float16* WgLoAll = (_Float16*)(ws + 14538752); // 5*48*384 f16
    _Float16* OutHi   = (_Float16*)(ws + 14584832); // 16*384 f16
    _Float16* OutLo   = (_Float16*)(ws + 14587904); // 16*384 f16

    dim3 blk(256);

    // ---- prep: input BN fold + all weight split-casts (up front)
    stats_partial<<<dim3(4, NPART), blk, 0, stream>>>(x, NIN, 0, psum, psq);
    stats_finalize<<<dim3(4), blk, 0, stream>>>(psum, psq, NIN, gamma_in, beta_in, avec, cvec);
    scale_win_hl<<<dim3((NH * NIN / 4 + 255) / 256), blk, 0, stream>>>(W_in, avec, WpHi, WpLo);
    bias_in<<<dim3(NH), dim3(64), 0, stream>>>(W_in, b_in, cvec, bp);
    conv_hl<<<dim3((5 * 36 * 4096 / 4 + 255) / 256), blk, 0, stream>>>(
            Wd, WdHiAll, WdLoAll, 5 * 36 * 4096 / 4);
    prep_wg<<<dim3((5 * 48 * 384 + 255) / 256), blk, 0, stream>>>(Wg, WgHiAll, WgLoAll);
    prep_wout<<<dim3((16 * 384 + 255) / 256), blk, 0, stream>>>(W_out, OutHi, OutLo);

    // ---- input GEMM (fp16x3 MFMA) -> pre f32
    gemm_in_mfma<<<dim3(BATCH / 128, 6), blk, 0, stream>>>(x, WpHi, WpLo, bp, pre);

    // ---- hidden layers
    for (int j = 0; j < NLAYERS; ++j) {
        stats_partial<<<dim3(2, NPART), blk, 0, stream>>>(pre, NH, 1, psum, psq);
        stats_finalize<<<dim3(2), blk, 0, stream>>>(psum, psq, NH,
                gamma_h + j * NH, beta_h + j * NH, avec, cvec);
        if (j < NLAYERS - 1) {
            int l = j;
            normgate_mfma<<<dim3(BATCH / 16), blk, 0, stream>>>(
                    pre, avec, cvec, WgHiAll + (size_t)l * 48 * 384,
                    WgLoAll + (size_t)l * 48 * 384, actsHi, actsLo, gateT, tg, l == 0);
            layer_data_mfma<<<dim3(BATCH / 64, 2), blk, 0, stream>>>(
                    actsHi, actsLo, gateT, WdHiAll + (size_t)l * 36 * 4096,
                    WdLoAll + (size_t)l * 36 * 4096, bd + (size_t)l * 36 * 64, pre);
        } else {
            normout_mfma<<<dim3(BATCH / 16), blk, 0, stream>>>(
                    pre, avec, cvec, OutHi, OutLo, tg, dout);
        }
    }
}